// Round 3
// baseline (755.271 us; speedup 1.0000x reference)
//
#include <hip/hip_runtime.h>
#include <stdint.h>

typedef unsigned short u16;
typedef __attribute__((ext_vector_type(8))) short short8;
typedef __attribute__((ext_vector_type(4))) float floatx4;

#define T_TOK 8192
#define DM 1024
#define NE 8
#define HD 1408

__device__ __forceinline__ float bf2f(u16 u) {
  union { float f; uint32_t i; } v; v.i = ((uint32_t)u) << 16; return v.f;
}
__device__ __forceinline__ u16 f2bf(float f) {
  union { float f; uint32_t i; } v; v.f = f;
  uint32_t r = v.i + 0x7fffu + ((v.i >> 16) & 1u);
  return (u16)(r >> 16);
}
__device__ __forceinline__ floatx4 mfma16(short8 a, short8 b, floatx4 c) {
  return __builtin_amdgcn_mfma_f32_16x16x32_bf16(a, b, c, 0, 0, 0);
}

// ---------------- dtype detect: bf16 vs fp32 input arrays ------------------
// Even-indexed u16 words of x: bf16 -> exponent bits near 127 (~100% in
// [100,135]); fp32 low-mantissa halves -> uniform (~14%). 64 samples.
__global__ void detect_k(const u16* __restrict__ xraw, int* __restrict__ flag) {
  int lane = threadIdx.x & 63;
  u16 w = xraw[lane * 2];
  int ex = (w >> 7) & 0xFF;
  bool hit = (ex >= 100 && ex <= 135);
  unsigned long long m = __ballot(hit);
  if (lane == 0) *flag = (__popcll(m) >= 40) ? 1 : 0;
}

// ---------------- alpha convert -> canonical bf16 --------------------------
__global__ void conv_alpha_k(const void* __restrict__ araw, u16* __restrict__ ab,
                             const int* __restrict__ flag) {
  int f = *flag;
  if (threadIdx.x < NE) {
    ab[threadIdx.x] = f ? ((const u16*)araw)[threadIdx.x]
                        : f2bf(((const float*)araw)[threadIdx.x]);
  }
}

// ---------------- x convert -> canonical bf16 (fp32 case only) -------------
__global__ __launch_bounds__(256) void conv_x_k(const void* __restrict__ xraw,
                                                u16* __restrict__ xb,
                                                const int* __restrict__ flag) {
  if (*flag) return;  // bf16 input: consumers read raw directly
  size_t base = ((size_t)blockIdx.x * 256 + threadIdx.x) * 8;
  const float* s = (const float*)xraw + base;
  float4 v0 = *(const float4*)s;
  float4 v1 = *(const float4*)(s + 4);
  ushort4 o0, o1;
  o0.x = f2bf(v0.x); o0.y = f2bf(v0.y); o0.z = f2bf(v0.z); o0.w = f2bf(v0.w);
  o1.x = f2bf(v1.x); o1.y = f2bf(v1.y); o1.z = f2bf(v1.z); o1.w = f2bf(v1.w);
  *(ushort4*)(xb + base) = o0;
  *(ushort4*)(xb + base + 4) = o1;
}

// ---------------- transpose+convert: src [E][R][C] -> dst bf16 [E][C][R] ---
__global__ __launch_bounds__(256) void transpose_k(
    const void* __restrict__ src, u16* __restrict__ dst, int R, int C,
    const u16* __restrict__ alphab, int mode, const int* __restrict__ flag) {
  int e = blockIdx.z;
  if (mode) {
    float a = bf2f(alphab[e]);
    if (mode == 1 && a == 1.0f) return;  // Wx unused when alpha==1
    if (mode == 2 && a == 0.0f) return;  // Wg unused when alpha==0
  }
  int f = *flag;
  __shared__ u16 tile[64][65];
  u16* d = dst + (size_t)e * R * C;
  int c0 = blockIdx.x * 64, r0 = blockIdx.y * 64;
  int tx = threadIdx.x & 63, ty = threadIdx.x >> 6;
  if (f) {
    const u16* s = (const u16*)src + (size_t)e * R * C;
    for (int i = ty; i < 64; i += 4)
      tile[i][tx] = s[(size_t)(r0 + i) * C + (c0 + tx)];
  } else {
    const float* s = (const float*)src + (size_t)e * R * C;
    for (int i = ty; i < 64; i += 4)
      tile[i][tx] = f2bf(s[(size_t)(r0 + i) * C + (c0 + tx)]);
  }
  __syncthreads();
  for (int i = ty; i < 64; i += 4)
    d[(size_t)(c0 + i) * R + (r0 + tx)] = tile[tx][i];
}

// ---------------- router: one wave per token (dual dtype) ------------------
__global__ __launch_bounds__(256) void router_k(
    const void* __restrict__ x, const void* __restrict__ Wr,
    int* __restrict__ counts, float* __restrict__ usage,
    int* __restrict__ tok_ids, float* __restrict__ tok_w,
    const int* __restrict__ flag) {
  __shared__ float sprob[4][8];
  int wave = threadIdx.x >> 6, lane = threadIdx.x & 63;
  int t = blockIdx.x * 4 + wave;
  int f = *flag;
  float acc[8];
  #pragma unroll
  for (int e = 0; e < 8; e++) acc[e] = 0.0f;
  if (f) {
    const u16* xr = (const u16*)x + (size_t)t * DM;
    const u16* wr = (const u16*)Wr;
    #pragma unroll
    for (int i = 0; i < 16; i++) {
      int d = i * 64 + lane;
      float xv = bf2f(xr[d]);
      uint4 wv = *(const uint4*)(wr + (size_t)d * 8);
      acc[0] += xv * bf2f((u16)(wv.x & 0xffff));
      acc[1] += xv * bf2f((u16)(wv.x >> 16));
      acc[2] += xv * bf2f((u16)(wv.y & 0xffff));
      acc[3] += xv * bf2f((u16)(wv.y >> 16));
      acc[4] += xv * bf2f((u16)(wv.z & 0xffff));
      acc[5] += xv * bf2f((u16)(wv.z >> 16));
      acc[6] += xv * bf2f((u16)(wv.w & 0xffff));
      acc[7] += xv * bf2f((u16)(wv.w >> 16));
    }
  } else {
    const float* xr = (const float*)x + (size_t)t * DM;
    const float* wr = (const float*)Wr;
    #pragma unroll
    for (int i = 0; i < 16; i++) {
      int d = i * 64 + lane;
      float xv = xr[d];
      float4 w0 = *(const float4*)(wr + (size_t)d * 8);
      float4 w1 = *(const float4*)(wr + (size_t)d * 8 + 4);
      acc[0] += xv * w0.x; acc[1] += xv * w0.y;
      acc[2] += xv * w0.z; acc[3] += xv * w0.w;
      acc[4] += xv * w1.x; acc[5] += xv * w1.y;
      acc[6] += xv * w1.z; acc[7] += xv * w1.w;
    }
  }
  #pragma unroll
  for (int e = 0; e < 8; e++) {
    #pragma unroll
    for (int s = 32; s; s >>= 1) acc[e] += __shfl_xor(acc[e], s, 64);
  }
  float mx = acc[0];
  #pragma unroll
  for (int e = 1; e < 8; e++) mx = fmaxf(mx, acc[e]);
  float p[8], sum = 0.0f;
  #pragma unroll
  for (int e = 0; e < 8; e++) { p[e] = __expf(acc[e] - mx); sum += p[e]; }
  float inv = 1.0f / sum;
  #pragma unroll
  for (int e = 0; e < 8; e++) p[e] *= inv;
  if (lane == 0) {
    #pragma unroll
    for (int e = 0; e < 8; e++) sprob[wave][e] = p[e];
    int e0 = 0;
    #pragma unroll
    for (int e = 1; e < 8; e++) if (p[e] > p[e0]) e0 = e;
    int e1 = (e0 == 0) ? 1 : 0;
    #pragma unroll
    for (int e = 0; e < 8; e++) if (e != e0 && p[e] > p[e1]) e1 = e;
    float s2 = 1.0f / (p[e0] + p[e1]);
    int i0 = atomicAdd(&counts[e0], 1);
    tok_ids[e0 * T_TOK + i0] = t; tok_w[e0 * T_TOK + i0] = p[e0] * s2;
    int i1 = atomicAdd(&counts[e1], 1);
    tok_ids[e1 * T_TOK + i1] = t; tok_w[e1 * T_TOK + i1] = p[e1] * s2;
  }
  __syncthreads();
  if (threadIdx.x < 8) {
    float s = sprob[0][threadIdx.x] + sprob[1][threadIdx.x] +
              sprob[2][threadIdx.x] + sprob[3][threadIdx.x];
    atomicAdd(&usage[threadIdx.x], s);
  }
}

__global__ void scan_k(const int* __restrict__ counts, int* __restrict__ offs) {
  if (threadIdx.x == 0) {
    int s = 0;
    for (int e = 0; e < 8; e++) { offs[e] = s; s += counts[e]; }
    offs[8] = s;
  }
}

// ---------------- stage A: gathered x @ {Wg,Wu,Wx}^T, fused silu-combine ----
__global__ __launch_bounds__(256, 2) void stageA_k(
    const void* __restrict__ xraw, const u16* __restrict__ xb,
    const u16* __restrict__ WgT, const u16* __restrict__ WuT,
    const u16* __restrict__ WxT, const u16* __restrict__ alphab,
    const int* __restrict__ counts, const int* __restrict__ offs,
    const int* __restrict__ tok_ids, u16* __restrict__ comb,
    const int* __restrict__ flag) {
  int e = blockIdx.z;
  int cnt = counts[e];
  int m0 = blockIdx.y * 128;
  if (m0 >= cnt) return;
  int h0 = blockIdx.x * 64;
  int rem = cnt - m0;
  const u16* x = (*flag) ? (const u16*)xraw : xb;

  alignas(16) __shared__ u16 sA[128 * 64];
  alignas(16) __shared__ u16 sG[64 * 64];
  alignas(16) __shared__ u16 sU[64 * 64];
  alignas(16) __shared__ u16 sX[64 * 64];
  __shared__ int sTok[128];

  int tid = threadIdx.x;
  if (tid < 128)
    sTok[tid] = tok_ids[e * T_TOK + ((tid < rem) ? (m0 + tid) : m0)];
  __syncthreads();

  float aE = bf2f(alphab[e]);
  bool needG = (aE != 0.0f);
  bool needX = (aE != 1.0f);

  const u16* wg = WgT + (size_t)e * HD * DM;
  const u16* wu = WuT + (size_t)e * HD * DM;
  const u16* wx = WxT + (size_t)e * HD * DM;

  int lane = tid & 63, wave = tid >> 6;
  int wm = wave & 1, wn = wave >> 1;
  int lr = lane & 15, quad = lane >> 4;

  int rowA[4], segA[4], rowW[2], segW[2];
  #pragma unroll
  for (int i = 0; i < 4; i++) { int f = tid + 256 * i; rowA[i] = f >> 3; segA[i] = f & 7; }
  #pragma unroll
  for (int i = 0; i < 2; i++) { int f = tid + 256 * i; rowW[i] = f >> 3; segW[i] = f & 7; }

  floatx4 accG[4][2], accU[4][2], accX[4][2];
  #pragma unroll
  for (int i = 0; i < 4; i++)
    #pragma unroll
    for (int j = 0; j < 2; j++) {
      accG[i][j] = (floatx4)0.0f; accU[i][j] = (floatx4)0.0f; accX[i][j] = (floatx4)0.0f;
    }

  short8 rA[4], rU[2], rG[2], rX[2];
  #pragma unroll
  for (int i = 0; i < 4; i++)
    rA[i] = *(const short8*)(x + (size_t)sTok[rowA[i]] * DM + segA[i] * 8);
  #pragma unroll
  for (int i = 0; i < 2; i++) {
    size_t go = (size_t)(h0 + rowW[i]) * DM + segW[i] * 8;
    rU[i] = *(const short8*)(wu + go);
    if (needG) rG[i] = *(const short8*)(wg + go);
    if (needX) rX[i] = *(const short8*)(wx + go);
  }

  const int NK = DM / 64;
  for (int kt = 0; kt < NK; kt++) {
    __syncthreads();
    #pragma unroll
    for (int i = 0; i < 4; i++) *(short8*)&sA[(tid + 256 * i) * 8] = rA[i];
    #pragma unroll
    for (int i = 0; i < 2; i++) {
      *(short8*)&sU[(tid + 256 * i) * 8] = rU[i];
      if (needG) *(short8*)&sG[(tid + 256 * i) * 8] = rG[i];
      if (needX) *(short8*)&sX[(tid + 256 * i) * 8] = rX[i];
    }
    __syncthreads();
    if (kt + 1 < NK) {
      int k0 = (kt + 1) * 64;
      #pragma unroll
      for (int i = 0; i < 4; i++)
        rA[i] = *(const short8*)(x + (size_t)sTok[rowA[i]] * DM + k0 + segA[i] * 8);
      #pragma unroll
      for (int i = 0; i < 2; i++) {
        size_t go = (size_t)(h0 + rowW[i]) * DM + k0 + segW[i] * 8;
        rU[i] = *(const short8*)(wu + go);
        if (needG) rG[i] = *(const short8*)(wg + go);
        if (needX) rX[i] = *(const short8*)(wx + go);
      }
    }
    #pragma unroll
    for (int kk = 0; kk < 2; kk++) {
      int kb = kk * 32 + quad * 8;
      short8 a[4];
      #pragma unroll
      for (int i = 0; i < 4; i++)
        a[i] = *(const short8*)&sA[(wm * 64 + i * 16 + lr) * 64 + kb];
      #pragma unroll
      for (int j = 0; j < 2; j++) {
        int nb = (wn * 32 + j * 16 + lr) * 64 + kb;
        short8 bu = *(const short8*)&sU[nb];
        #pragma unroll
        for (int i = 0; i < 4; i++) accU[i][j] = mfma16(a[i], bu, accU[i][j]);
        if (needG) {
          short8 bg = *(const short8*)&sG[nb];
          #pragma unroll
          for (int i = 0; i < 4; i++) accG[i][j] = mfma16(a[i], bg, accG[i][j]);
        }
        if (needX) {
          short8 bx = *(const short8*)&sX[nb];
          #pragma unroll
          for (int i = 0; i < 4; i++) accX[i][j] = mfma16(a[i], bx, accX[i][j]);
        }
      }
    }
  }

  float a1 = aE, a2 = 1.0f - aE;
  size_t rbase = (size_t)(offs[e] + m0);
  #pragma unroll
  for (int i = 0; i < 4; i++) {
    #pragma unroll
    for (int r = 0; r < 4; r++) {
      int row = wm * 64 + i * 16 + quad * 4 + r;
      if (row < rem) {
        u16* cp = comb + (rbase + row) * HD + h0 + wn * 32 + lr;
        #pragma unroll
        for (int j = 0; j < 2; j++) {
          float g = accG[i][j][r], u = accU[i][j][r], xx = accX[i][j][r];
          float sg = g / (1.0f + __expf(-g));
          float sx = xx / (1.0f + __expf(-xx));
          cp[j * 16] = f2bf(u * (a1 * sg + a2 * sx));
        }
      }
    }
  }
}

// ---------------- stage B: combined @ WdT, scaled scatter-accumulate -------
__global__ __launch_bounds__(256, 2) void stageB_k(
    const u16* __restrict__ comb, const u16* __restrict__ WdT,
    const int* __restrict__ counts, const int* __restrict__ offs,
    const int* __restrict__ tok_ids, const float* __restrict__ tok_w,
    float* __restrict__ accb) {
  int e = blockIdx.z;
  int cnt = counts[e];
  int m0 = blockIdx.y * 128;
  if (m0 >= cnt) return;
  int d0 = blockIdx.x * 128;
  int rem = cnt - m0;

  alignas(16) __shared__ u16 sA[128 * 64];
  alignas(16) __shared__ u16 sB[128 * 64];
  __shared__ int sTok[128];
  __shared__ float sW[128];

  int tid = threadIdx.x;
  if (tid < 128) {
    bool v = tid < rem;
    sTok[tid] = v ? tok_ids[e * T_TOK + m0 + tid] : 0;
    sW[tid] = v ? tok_w[e * T_TOK + m0 + tid] : 0.0f;
  }
  __syncthreads();

  const u16* ca = comb + (size_t)(offs[e] + m0) * HD;
  const u16* wd = WdT + (size_t)e * DM * HD;

  int lane = tid & 63, wave = tid >> 6;
  int wm = wave & 1, wn = wave >> 1;
  int lr = lane & 15, quad = lane >> 4;

  int rowS[4], segS[4], rowC[4];
  #pragma unroll
  for (int i = 0; i < 4; i++) {
    int f = tid + 256 * i;
    rowS[i] = f >> 3; segS[i] = f & 7;
    rowC[i] = (rowS[i] < rem) ? rowS[i] : 0;
  }

  floatx4 acc[4][4];
  #pragma unroll
  for (int i = 0; i < 4; i++)
    #pragma unroll
    for (int j = 0; j < 4; j++) acc[i][j] = (floatx4)0.0f;

  short8 rAr[4], rBr[4];
  #pragma unroll
  for (int i = 0; i < 4; i++) {
    rAr[i] = *(const short8*)(ca + (size_t)rowC[i] * HD + segS[i] * 8);
    rBr[i] = *(const short8*)(wd + (size_t)(d0 + rowS[i]) * HD + segS[i] * 8);
  }

  const int NK = HD / 64;
  for (int kt = 0; kt < NK; kt++) {
    __syncthreads();
    #pragma unroll
    for (int i = 0; i < 4; i++) {
      *(short8*)&sA[(tid + 256 * i) * 8] = rAr[i];
      *(short8*)&sB[(tid + 256 * i) * 8] = rBr[i];
    }
    __syncthreads();
    if (kt + 1 < NK) {
      int k0 = (kt + 1) * 64;
      #pragma unroll
      for (int i = 0; i < 4; i++) {
        rAr[i] = *(const short8*)(ca + (size_t)rowC[i] * HD + k0 + segS[i] * 8);
        rBr[i] = *(const short8*)(wd + (size_t)(d0 + rowS[i]) * HD + k0 + segS[i] * 8);
      }
    }
    #pragma unroll
    for (int kk = 0; kk < 2; kk++) {
      int kb = kk * 32 + quad * 8;
      short8 a[4];
      #pragma unroll
      for (int i = 0; i < 4; i++)
        a[i] = *(const short8*)&sA[(wm * 64 + i * 16 + lr) * 64 + kb];
      #pragma unroll
      for (int j = 0; j < 4; j++) {
        short8 b = *(const short8*)&sB[(wn * 64 + j * 16 + lr) * 64 + kb];
        #pragma unroll
        for (int i = 0; i < 4; i++) acc[i][j] = mfma16(a[i], b, acc[i][j]);
      }
    }
  }

  #pragma unroll
  for (int i = 0; i < 4; i++) {
    #pragma unroll
    for (int r = 0; r < 4; r++) {
      int row = wm * 64 + i * 16 + quad * 4 + r;
      if (row < rem) {
        int t = sTok[row];
        float w = sW[row];
        float* orow = accb + (size_t)t * DM + d0 + wn * 64 + lr;
        #pragma unroll
        for (int j = 0; j < 4; j++)
          atomicAdd(&orow[j * 16], acc[i][j][r] * w);
      }
    }
  }
}

// ---------------- finalize: fp32 accum -> out (dual dtype), lb scalar ------
__global__ __launch_bounds__(256) void finalize_k(
    const float* __restrict__ accb, const float* __restrict__ usage,
    void* __restrict__ out, const int* __restrict__ flag) {
  int f = *flag;
  size_t idx = (size_t)blockIdx.x * 256 + threadIdx.x;
  float4 v = ((const float4*)accb)[idx];
  float lb = 0.0f;
  if (idx == 0) {
    for (int e = 0; e < 8; e++) {
      float d = usage[e] * (1.0f / 8192.0f) - 0.125f;
      lb += d * d;
    }
    lb *= 0.01f * 0.125f;
  }
  if (f) {
    u16* o = (u16*)out;
    ushort4 ov;
    ov.x = f2bf(v.x); ov.y = f2bf(v.y); ov.z = f2bf(v.z); ov.w = f2bf(v.w);
    ((ushort4*)o)[idx] = ov;
    if (idx == 0) o[(size_t)T_TOK * DM] = f2bf(lb);
  } else {
    float* o = (float*)out;
    ((float4*)o)[idx] = v;
    if (idx == 0) o[(size_t)T_TOK * DM] = lb;
  }
}

extern "C" void kernel_launch(void* const* d_in, const int* in_sizes, int n_in,
                              void* d_out, int out_size, void* d_ws, size_t ws_size,
                              hipStream_t stream) {
  const void* x  = d_in[0];
  const void* Wr = d_in[1];
  const void* Wg = d_in[2];
  const void* Wu = d_in[3];
  const void* Wx = d_in[4];
  const void* Wd = d_in[5];
  const void* al = d_in[6];
  char* ws = (char*)d_ws;

  // ws layout (bytes, all 64-aligned):
  int*   counts  = (int*)(ws + 0);           // 32
  float* usage   = (float*)(ws + 32);        // 32
  int*   flag    = (int*)(ws + 64);          // pad to 128
  float* accb    = (float*)(ws + 128);       // 33,554,432
  int*   offs    = (int*)(ws + 33554560);    // 64
  int*   tok_ids = (int*)(ws + 33554624);    // 262,144
  float* tok_w   = (float*)(ws + 33816768);  // 262,144
  u16*   alphab  = (u16*)(ws + 34078912);    // 64
  u16*   xb      = (u16*)(ws + 34078976);    // 16,777,216
  u16*   comb    = (u16*)(ws + 50856192);    // 46,137,344
  u16*   WgT     = (u16*)(ws + 96993536);    // 23,068,672
  u16*   WuT     = (u16*)(ws + 120062208);   // 23,068,672
  u16*   WdT     = (u16*)(ws + 143130880);   // 23,068,672
  u16*   WxT     = (u16*)(ws + 166199552);   // 23,068,672 (touched only if alpha!=1)

  hipMemsetAsync(ws, 0, 33554560, stream);  // counts+usage+flag+accb

  dim3 b256(256, 1, 1);
  detect_k<<<dim3(1), dim3(64), 0, stream>>>((const u16*)x, flag);
  conv_alpha_k<<<dim3(1), dim3(64), 0, stream>>>(al, alphab, flag);
  conv_x_k<<<dim3(4096), b256, 0, stream>>>(x, xb, flag);
  transpose_k<<<dim3(HD / 64, DM / 64, NE), b256, 0, stream>>>(Wg, WgT, DM, HD, alphab, 2, flag);
  transpose_k<<<dim3(HD / 64, DM / 64, NE), b256, 0, stream>>>(Wu, WuT, DM, HD, alphab, 0, flag);
  transpose_k<<<dim3(HD / 64, DM / 64, NE), b256, 0, stream>>>(Wx, WxT, DM, HD, alphab, 1, flag);
  transpose_k<<<dim3(DM / 64, HD / 64, NE), b256, 0, stream>>>(Wd, WdT, HD, DM, alphab, 0, flag);
  router_k<<<dim3(T_TOK / 4), b256, 0, stream>>>(x, Wr, counts, usage, tok_ids, tok_w, flag);
  scan_k<<<dim3(1), dim3(64), 0, stream>>>(counts, offs);
  stageA_k<<<dim3(HD / 64, T_TOK / 128, NE), b256, 0, stream>>>(
      x, xb, WgT, WuT, WxT, alphab, counts, offs, tok_ids, comb, flag);
  stageB_k<<<dim3(DM / 128, T_TOK / 128, NE), b256, 0, stream>>>(
      comb, WdT, counts, offs, tok_ids, tok_w, accb);
  finalize_k<<<dim3((T_TOK * DM / 4) / 256), b256, 0, stream>>>(accb, usage, d_out, flag);
}

// Round 4
// 555.431 us; speedup vs baseline: 1.3598x; 1.3598x over previous
//
#include <hip/hip_runtime.h>
#include <stdint.h>

typedef unsigned short u16;
typedef __attribute__((ext_vector_type(8))) short short8;
typedef __attribute__((ext_vector_type(4))) float floatx4;

#define T_TOK 8192
#define DM 1024
#define NE 8
#define HD 1408

__device__ __forceinline__ float bf2f(u16 u) {
  union { float f; uint32_t i; } v; v.i = ((uint32_t)u) << 16; return v.f;
}
__device__ __forceinline__ u16 f2bf(float f) {
  union { float f; uint32_t i; } v; v.f = f;
  uint32_t r = v.i + 0x7fffu + ((v.i >> 16) & 1u);
  return (u16)(r >> 16);
}
__device__ __forceinline__ floatx4 mfma16(short8 a, short8 b, floatx4 c) {
  return __builtin_amdgcn_mfma_f32_16x16x32_bf16(a, b, c, 0, 0, 0);
}

// ---------------- dtype detect: bf16 vs fp32 input arrays ------------------
__global__ void detect_k(const u16* __restrict__ xraw, int* __restrict__ flag) {
  int lane = threadIdx.x & 63;
  u16 w = xraw[lane * 2];
  int ex = (w >> 7) & 0xFF;
  bool hit = (ex >= 100 && ex <= 135);
  unsigned long long m = __ballot(hit);
  if (lane == 0) *flag = (__popcll(m) >= 40) ? 1 : 0;
}

// ---------------- alpha convert -> canonical bf16 --------------------------
__global__ void conv_alpha_k(const void* __restrict__ araw, u16* __restrict__ ab,
                             const int* __restrict__ flag) {
  int f = *flag;
  if (threadIdx.x < NE) {
    ab[threadIdx.x] = f ? ((const u16*)araw)[threadIdx.x]
                        : f2bf(((const float*)araw)[threadIdx.x]);
  }
}

// ---------------- x convert -> canonical bf16 (fp32 case only) -------------
__global__ __launch_bounds__(256) void conv_x_k(const void* __restrict__ xraw,
                                                u16* __restrict__ xb,
                                                const int* __restrict__ flag) {
  if (*flag) return;
  size_t base = ((size_t)blockIdx.x * 256 + threadIdx.x) * 8;
  const float* s = (const float*)xraw + base;
  float4 v0 = *(const float4*)s;
  float4 v1 = *(const float4*)(s + 4);
  ushort4 o0, o1;
  o0.x = f2bf(v0.x); o0.y = f2bf(v0.y); o0.z = f2bf(v0.z); o0.w = f2bf(v0.w);
  o1.x = f2bf(v1.x); o1.y = f2bf(v1.y); o1.z = f2bf(v1.z); o1.w = f2bf(v1.w);
  *(ushort4*)(xb + base) = o0;
  *(ushort4*)(xb + base + 4) = o1;
}

// ---------------- transpose+convert: src [E][R][C] -> dst bf16 [E][C][R] ---
__global__ __launch_bounds__(256) void transpose_k(
    const void* __restrict__ src, u16* __restrict__ dst, int R, int C,
    const u16* __restrict__ alphab, int mode, const int* __restrict__ flag) {
  int e = blockIdx.z;
  if (mode) {
    float a = bf2f(alphab[e]);
    if (mode == 1 && a == 1.0f) return;  // Wx unused when alpha==1
    if (mode == 2 && a == 0.0f) return;  // Wg unused when alpha==0
  }
  int f = *flag;
  __shared__ u16 tile[64][65];
  u16* d = dst + (size_t)e * R * C;
  int c0 = blockIdx.x * 64, r0 = blockIdx.y * 64;
  int tx = threadIdx.x & 63, ty = threadIdx.x >> 6;
  if (f) {
    const u16* s = (const u16*)src + (size_t)e * R * C;
    for (int i = ty; i < 64; i += 4)
      tile[i][tx] = s[(size_t)(r0 + i) * C + (c0 + tx)];
  } else {
    const float* s = (const float*)src + (size_t)e * R * C;
    for (int i = ty; i < 64; i += 4)
      tile[i][tx] = f2bf(s[(size_t)(r0 + i) * C + (c0 + tx)]);
  }
  __syncthreads();
  for (int i = ty; i < 64; i += 4)
    d[(size_t)(c0 + i) * R + (r0 + tx)] = tile[tx][i];
}

// ---------------- router phase 1: logits+softmax, NO atomics ---------------
__global__ __launch_bounds__(256) void rdot_k(
    const void* __restrict__ x, const void* __restrict__ Wr,
    float* __restrict__ probs, const int* __restrict__ flag) {
  int wave = threadIdx.x >> 6, lane = threadIdx.x & 63;
  int t = blockIdx.x * 4 + wave;
  int f = *flag;
  float acc[8];
  #pragma unroll
  for (int e = 0; e < 8; e++) acc[e] = 0.0f;
  if (f) {
    const u16* xr = (const u16*)x + (size_t)t * DM;
    const u16* wr = (const u16*)Wr;
    #pragma unroll
    for (int i = 0; i < 16; i++) {
      int d = i * 64 + lane;
      float xv = bf2f(xr[d]);
      uint4 wv = *(const uint4*)(wr + (size_t)d * 8);
      acc[0] += xv * bf2f((u16)(wv.x & 0xffff));
      acc[1] += xv * bf2f((u16)(wv.x >> 16));
      acc[2] += xv * bf2f((u16)(wv.y & 0xffff));
      acc[3] += xv * bf2f((u16)(wv.y >> 16));
      acc[4] += xv * bf2f((u16)(wv.z & 0xffff));
      acc[5] += xv * bf2f((u16)(wv.z >> 16));
      acc[6] += xv * bf2f((u16)(wv.w & 0xffff));
      acc[7] += xv * bf2f((u16)(wv.w >> 16));
    }
  } else {
    const float* xr = (const float*)x + (size_t)t * DM;
    const float* wr = (const float*)Wr;
    #pragma unroll
    for (int i = 0; i < 16; i++) {
      int d = i * 64 + lane;
      float xv = xr[d];
      float4 w0 = *(const float4*)(wr + (size_t)d * 8);
      float4 w1 = *(const float4*)(wr + (size_t)d * 8 + 4);
      acc[0] += xv * w0.x; acc[1] += xv * w0.y;
      acc[2] += xv * w0.z; acc[3] += xv * w0.w;
      acc[4] += xv * w1.x; acc[5] += xv * w1.y;
      acc[6] += xv * w1.z; acc[7] += xv * w1.w;
    }
  }
  #pragma unroll
  for (int e = 0; e < 8; e++) {
    #pragma unroll
    for (int s = 32; s; s >>= 1) acc[e] += __shfl_xor(acc[e], s, 64);
  }
  float mx = acc[0];
  #pragma unroll
  for (int e = 1; e < 8; e++) mx = fmaxf(mx, acc[e]);
  float p[8], sum = 0.0f;
  #pragma unroll
  for (int e = 0; e < 8; e++) { p[e] = __expf(acc[e] - mx); sum += p[e]; }
  float inv = 1.0f / sum;
  if (lane < 8) probs[(size_t)t * 8 + lane] = p[lane] * inv;
}

// ---------------- router phase 2: build expert lists (few atomics) ---------
// 32 blocks x 256 tokens; per-block LDS histogram -> 8 global fetch-adds.
__global__ __launch_bounds__(256) void build_k(
    const float* __restrict__ probs, int* __restrict__ counts,
    float* __restrict__ usage, int* __restrict__ tok_ids,
    float* __restrict__ tok_w) {
  __shared__ int sCnt[8];
  __shared__ int sBase[8];
  __shared__ float sUse[8];
  int tid = threadIdx.x;
  if (tid < 8) { sCnt[tid] = 0; sUse[tid] = 0.0f; }
  __syncthreads();

  int t = blockIdx.x * 256 + tid;
  float4 p0 = *(const float4*)(probs + (size_t)t * 8);
  float4 p1 = *(const float4*)(probs + (size_t)t * 8 + 4);
  float p[8] = {p0.x, p0.y, p0.z, p0.w, p1.x, p1.y, p1.z, p1.w};

  // usage partials: wave-level shuffle reduce, then LDS accumulate
  #pragma unroll
  for (int e = 0; e < 8; e++) {
    float v = p[e];
    #pragma unroll
    for (int s = 32; s; s >>= 1) v += __shfl_xor(v, s, 64);
    if ((tid & 63) == 0) atomicAdd(&sUse[e], v);
  }

  // top-2 (ties -> lower index, matches lax.top_k)
  int e0 = 0;
  #pragma unroll
  for (int e = 1; e < 8; e++) if (p[e] > p[e0]) e0 = e;
  int e1 = (e0 == 0) ? 1 : 0;
  #pragma unroll
  for (int e = 0; e < 8; e++) if (e != e0 && p[e] > p[e1]) e1 = e;
  float s2 = 1.0f / (p[e0] + p[e1]);

  int s0 = atomicAdd(&sCnt[e0], 1);
  int s1 = atomicAdd(&sCnt[e1], 1);
  __syncthreads();
  if (tid < 8) {
    sBase[tid] = atomicAdd(&counts[tid], sCnt[tid]);
    atomicAdd(&usage[tid], sUse[tid]);
  }
  __syncthreads();
  int i0 = sBase[e0] + s0;
  tok_ids[e0 * T_TOK + i0] = t; tok_w[e0 * T_TOK + i0] = p[e0] * s2;
  int i1 = sBase[e1] + s1;
  tok_ids[e1 * T_TOK + i1] = t; tok_w[e1 * T_TOK + i1] = p[e1] * s2;
}

__global__ void scan_k(const int* __restrict__ counts, int* __restrict__ offs) {
  if (threadIdx.x == 0) {
    int s = 0;
    for (int e = 0; e < 8; e++) { offs[e] = s; s += counts[e]; }
    offs[8] = s;
  }
}

// ---------------- stage A: gathered x @ {Wg,Wu,Wx}^T, fused silu-combine ----
__global__ __launch_bounds__(256, 2) void stageA_k(
    const void* __restrict__ xraw, const u16* __restrict__ xb,
    const u16* __restrict__ WgT, const u16* __restrict__ WuT,
    const u16* __restrict__ WxT, const u16* __restrict__ alphab,
    const int* __restrict__ counts, const int* __restrict__ offs,
    const int* __restrict__ tok_ids, u16* __restrict__ comb,
    const int* __restrict__ flag) {
  int e = blockIdx.z;
  int cnt = counts[e];
  int m0 = blockIdx.y * 128;
  if (m0 >= cnt) return;
  int h0 = blockIdx.x * 64;
  int rem = cnt - m0;
  const u16* x = (*flag) ? (const u16*)xraw : xb;

  alignas(16) __shared__ u16 sA[128 * 64];
  alignas(16) __shared__ u16 sG[64 * 64];
  alignas(16) __shared__ u16 sU[64 * 64];
  alignas(16) __shared__ u16 sX[64 * 64];
  __shared__ int sTok[128];

  int tid = threadIdx.x;
  if (tid < 128)
    sTok[tid] = tok_ids[e * T_TOK + ((tid < rem) ? (m0 + tid) : m0)];
  __syncthreads();

  float aE = bf2f(alphab[e]);
  bool needG = (aE != 0.0f);
  bool needX = (aE != 1.0f);

  const u16* wg = WgT + (size_t)e * HD * DM;
  const u16* wu = WuT + (size_t)e * HD * DM;
  const u16* wx = WxT + (size_t)e * HD * DM;

  int lane = tid & 63, wave = tid >> 6;
  int wm = wave & 1, wn = wave >> 1;
  int lr = lane & 15, quad = lane >> 4;

  int rowA[4], segA[4], rowW[2], segW[2];
  #pragma unroll
  for (int i = 0; i < 4; i++) { int f = tid + 256 * i; rowA[i] = f >> 3; segA[i] = f & 7; }
  #pragma unroll
  for (int i = 0; i < 2; i++) { int f = tid + 256 * i; rowW[i] = f >> 3; segW[i] = f & 7; }

  floatx4 accG[4][2], accU[4][2], accX[4][2];
  #pragma unroll
  for (int i = 0; i < 4; i++)
    #pragma unroll
    for (int j = 0; j < 2; j++) {
      accG[i][j] = (floatx4)0.0f; accU[i][j] = (floatx4)0.0f; accX[i][j] = (floatx4)0.0f;
    }

  short8 rA[4], rU[2], rG[2], rX[2];
  #pragma unroll
  for (int i = 0; i < 4; i++)
    rA[i] = *(const short8*)(x + (size_t)sTok[rowA[i]] * DM + segA[i] * 8);
  #pragma unroll
  for (int i = 0; i < 2; i++) {
    size_t go = (size_t)(h0 + rowW[i]) * DM + segW[i] * 8;
    rU[i] = *(const short8*)(wu + go);
    if (needG) rG[i] = *(const short8*)(wg + go);
    if (needX) rX[i] = *(const short8*)(wx + go);
  }

  const int NK = DM / 64;
  for (int kt = 0; kt < NK; kt++) {
    __syncthreads();
    #pragma unroll
    for (int i = 0; i < 4; i++) *(short8*)&sA[(tid + 256 * i) * 8] = rA[i];
    #pragma unroll
    for (int i = 0; i < 2; i++) {
      *(short8*)&sU[(tid + 256 * i) * 8] = rU[i];
      if (needG) *(short8*)&sG[(tid + 256 * i) * 8] = rG[i];
      if (needX) *(short8*)&sX[(tid + 256 * i) * 8] = rX[i];
    }
    __syncthreads();
    if (kt + 1 < NK) {
      int k0 = (kt + 1) * 64;
      #pragma unroll
      for (int i = 0; i < 4; i++)
        rA[i] = *(const short8*)(x + (size_t)sTok[rowA[i]] * DM + k0 + segA[i] * 8);
      #pragma unroll
      for (int i = 0; i < 2; i++) {
        size_t go = (size_t)(h0 + rowW[i]) * DM + k0 + segW[i] * 8;
        rU[i] = *(const short8*)(wu + go);
        if (needG) rG[i] = *(const short8*)(wg + go);
        if (needX) rX[i] = *(const short8*)(wx + go);
      }
    }
    #pragma unroll
    for (int kk = 0; kk < 2; kk++) {
      int kb = kk * 32 + quad * 8;
      short8 a[4];
      #pragma unroll
      for (int i = 0; i < 4; i++)
        a[i] = *(const short8*)&sA[(wm * 64 + i * 16 + lr) * 64 + kb];
      #pragma unroll
      for (int j = 0; j < 2; j++) {
        int nb = (wn * 32 + j * 16 + lr) * 64 + kb;
        short8 bu = *(const short8*)&sU[nb];
        #pragma unroll
        for (int i = 0; i < 4; i++) accU[i][j] = mfma16(a[i], bu, accU[i][j]);
        if (needG) {
          short8 bg = *(const short8*)&sG[nb];
          #pragma unroll
          for (int i = 0; i < 4; i++) accG[i][j] = mfma16(a[i], bg, accG[i][j]);
        }
        if (needX) {
          short8 bx = *(const short8*)&sX[nb];
          #pragma unroll
          for (int i = 0; i < 4; i++) accX[i][j] = mfma16(a[i], bx, accX[i][j]);
        }
      }
    }
  }

  float a1 = aE, a2 = 1.0f - aE;
  size_t rbase = (size_t)(offs[e] + m0);
  #pragma unroll
  for (int i = 0; i < 4; i++) {
    #pragma unroll
    for (int r = 0; r < 4; r++) {
      int row = wm * 64 + i * 16 + quad * 4 + r;
      if (row < rem) {
        u16* cp = comb + (rbase + row) * HD + h0 + wn * 32 + lr;
        #pragma unroll
        for (int j = 0; j < 2; j++) {
          float g = accG[i][j][r], u = accU[i][j][r], xx = accX[i][j][r];
          float sg = g / (1.0f + __expf(-g));
          float sx = xx / (1.0f + __expf(-xx));
          cp[j * 16] = f2bf(u * (a1 * sg + a2 * sx));
        }
      }
    }
  }
}

// ---------------- stage B: combined @ WdT, scaled scatter-accumulate -------
__global__ __launch_bounds__(256, 2) void stageB_k(
    const u16* __restrict__ comb, const u16* __restrict__ WdT,
    const int* __restrict__ counts, const int* __restrict__ offs,
    const int* __restrict__ tok_ids, const float* __restrict__ tok_w,
    float* __restrict__ accb) {
  int e = blockIdx.z;
  int cnt = counts[e];
  int m0 = blockIdx.y * 128;
  if (m0 >= cnt) return;
  int d0 = blockIdx.x * 128;
  int rem = cnt - m0;

  alignas(16) __shared__ u16 sA[128 * 64];
  alignas(16) __shared__ u16 sB[128 * 64];
  __shared__ int sTok[128];
  __shared__ float sW[128];

  int tid = threadIdx.x;
  if (tid < 128) {
    bool v = tid < rem;
    sTok[tid] = v ? tok_ids[e * T_TOK + m0 + tid] : 0;
    sW[tid] = v ? tok_w[e * T_TOK + m0 + tid] : 0.0f;
  }
  __syncthreads();

  const u16* ca = comb + (size_t)(offs[e] + m0) * HD;
  const u16* wd = WdT + (size_t)e * DM * HD;

  int lane = tid & 63, wave = tid >> 6;
  int wm = wave & 1, wn = wave >> 1;
  int lr = lane & 15, quad = lane >> 4;

  int rowS[4], segS[4], rowC[4];
  #pragma unroll
  for (int i = 0; i < 4; i++) {
    int f = tid + 256 * i;
    rowS[i] = f >> 3; segS[i] = f & 7;
    rowC[i] = (rowS[i] < rem) ? rowS[i] : 0;
  }

  floatx4 acc[4][4];
  #pragma unroll
  for (int i = 0; i < 4; i++)
    #pragma unroll
    for (int j = 0; j < 4; j++) acc[i][j] = (floatx4)0.0f;

  short8 rAr[4], rBr[4];
  #pragma unroll
  for (int i = 0; i < 4; i++) {
    rAr[i] = *(const short8*)(ca + (size_t)rowC[i] * HD + segS[i] * 8);
    rBr[i] = *(const short8*)(wd + (size_t)(d0 + rowS[i]) * HD + segS[i] * 8);
  }

  const int NK = HD / 64;
  for (int kt = 0; kt < NK; kt++) {
    __syncthreads();
    #pragma unroll
    for (int i = 0; i < 4; i++) {
      *(short8*)&sA[(tid + 256 * i) * 8] = rAr[i];
      *(short8*)&sB[(tid + 256 * i) * 8] = rBr[i];
    }
    __syncthreads();
    if (kt + 1 < NK) {
      int k0 = (kt + 1) * 64;
      #pragma unroll
      for (int i = 0; i < 4; i++) {
        rAr[i] = *(const short8*)(ca + (size_t)rowC[i] * HD + k0 + segS[i] * 8);
        rBr[i] = *(const short8*)(wd + (size_t)(d0 + rowS[i]) * HD + k0 + segS[i] * 8);
      }
    }
    #pragma unroll
    for (int kk = 0; kk < 2; kk++) {
      int kb = kk * 32 + quad * 8;
      short8 a[4];
      #pragma unroll
      for (int i = 0; i < 4; i++)
        a[i] = *(const short8*)&sA[(wm * 64 + i * 16 + lr) * 64 + kb];
      #pragma unroll
      for (int j = 0; j < 4; j++) {
        short8 b = *(const short8*)&sB[(wn * 64 + j * 16 + lr) * 64 + kb];
        #pragma unroll
        for (int i = 0; i < 4; i++) acc[i][j] = mfma16(a[i], b, acc[i][j]);
      }
    }
  }

  #pragma unroll
  for (int i = 0; i < 4; i++) {
    #pragma unroll
    for (int r = 0; r < 4; r++) {
      int row = wm * 64 + i * 16 + quad * 4 + r;
      if (row < rem) {
        int t = sTok[row];
        float w = sW[row];
        float* orow = accb + (size_t)t * DM + d0 + wn * 64 + lr;
        #pragma unroll
        for (int j = 0; j < 4; j++)
          atomicAdd(&orow[j * 16], acc[i][j][r] * w);
      }
    }
  }
}

// ---------------- finalize: fp32 accum -> out (dual dtype), lb scalar ------
__global__ __launch_bounds__(256) void finalize_k(
    const float* __restrict__ accb, const float* __restrict__ usage,
    void* __restrict__ out, const int* __restrict__ flag) {
  int f = *flag;
  size_t idx = (size_t)blockIdx.x * 256 + threadIdx.x;
  float4 v = ((const float4*)accb)[idx];
  float lb = 0.0f;
  if (idx == 0) {
    for (int e = 0; e < 8; e++) {
      float d = usage[e] * (1.0f / 8192.0f) - 0.125f;
      lb += d * d;
    }
    lb *= 0.01f * 0.125f;
  }
  if (f) {
    u16* o = (u16*)out;
    ushort4 ov;
    ov.x = f2bf(v.x); ov.y = f2bf(v.y); ov.z = f2bf(v.z); ov.w = f2bf(v.w);
    ((ushort4*)o)[idx] = ov;
    if (idx == 0) o[(size_t)T_TOK * DM] = f2bf(lb);
  } else {
    float* o = (float*)out;
    ((float4*)o)[idx] = v;
    if (idx == 0) o[(size_t)T_TOK * DM] = lb;
  }
}

extern "C" void kernel_launch(void* const* d_in, const int* in_sizes, int n_in,
                              void* d_out, int out_size, void* d_ws, size_t ws_size,
                              hipStream_t stream) {
  const void* x  = d_in[0];
  const void* Wr = d_in[1];
  const void* Wg = d_in[2];
  const void* Wu = d_in[3];
  const void* Wx = d_in[4];
  const void* Wd = d_in[5];
  const void* al = d_in[6];
  char* ws = (char*)d_ws;

  int*   counts  = (int*)(ws + 0);           // 32
  float* usage   = (float*)(ws + 32);        // 32
  int*   flag    = (int*)(ws + 64);          // pad to 128
  float* accb    = (float*)(ws + 128);       // 33,554,432
  int*   offs    = (int*)(ws + 33554560);    // 64
  int*   tok_ids = (int*)(ws + 33554624);    // 262,144
  float* tok_w   = (float*)(ws + 33816768);  // 262,144
  u16*   alphab  = (u16*)(ws + 34078912);    // 64
  u16*   xb      = (u16*)(ws + 34078976);    // 16,777,216
  u16*   comb    = (u16*)(ws + 50856192);    // 46,137,344
  u16*   WgT     = (u16*)(ws + 96993536);    // 23,068,672
  u16*   WuT     = (u16*)(ws + 120062208);   // 23,068,672
  u16*   WdT     = (u16*)(ws + 143130880);   // 23,068,672
  float* probs   = (float*)(ws + 166199552); // 262,144
  u16*   WxT     = (u16*)(ws + 166461696);   // 23,068,672 (touched only if alpha!=1)

  hipMemsetAsync(ws, 0, 33554560, stream);  // counts+usage+flag+accb

  dim3 b256(256, 1, 1);
  detect_k<<<dim3(1), dim3(64), 0, stream>>>((const u16*)x, flag);
  conv_alpha_k<<<dim3(1), dim3(64), 0, stream>>>(al, alphab, flag);
  conv_x_k<<<dim3(4096), b256, 0, stream>>>(x, xb, flag);
  transpose_k<<<dim3(HD / 64, DM / 64, NE), b256, 0, stream>>>(Wg, WgT, DM, HD, alphab, 2, flag);
  transpose_k<<<dim3(HD / 64, DM / 64, NE), b256, 0, stream>>>(Wu, WuT, DM, HD, alphab, 0, flag);
  transpose_k<<<dim3(HD / 64, DM / 64, NE), b256, 0, stream>>>(Wx, WxT, DM, HD, alphab, 1, flag);
  transpose_k<<<dim3(DM / 64, HD / 64, NE), b256, 0, stream>>>(Wd, WdT, HD, DM, alphab, 0, flag);
  rdot_k<<<dim3(T_TOK / 4), b256, 0, stream>>>(x, Wr, probs, flag);
  build_k<<<dim3(T_TOK / 256), b256, 0, stream>>>(probs, counts, usage, tok_ids, tok_w);
  scan_k<<<dim3(1), dim3(64), 0, stream>>>(counts, offs);
  stageA_k<<<dim3(HD / 64, T_TOK / 128, NE), b256, 0, stream>>>(
      x, xb, WgT, WuT, WxT, alphab, counts, offs, tok_ids, comb, flag);
  stageB_k<<<dim3(DM / 128, T_TOK / 128, NE), b256, 0, stream>>>(
      comb, WdT, counts, offs, tok_ids, tok_w, accb);
  finalize_k<<<dim3((T_TOK * DM / 4) / 256), b256, 0, stream>>>(accb, usage, d_out, flag);
}

// Round 5
// 520.744 us; speedup vs baseline: 1.4504x; 1.0666x over previous
//
#include <hip/hip_runtime.h>
#include <stdint.h>

typedef unsigned short u16;
typedef __attribute__((ext_vector_type(8))) short short8;
typedef __attribute__((ext_vector_type(4))) float floatx4;

#define T_TOK 8192
#define DM 1024
#define NE 8
#define HD 1408
#define LDA 72  // LDS row stride in u16: 144 B = 36 dwords -> bank stride 4,
                // ds_read_b128 x 64 lanes = 8 dwords/bank (floor). 64 was 2x.

__device__ __forceinline__ float bf2f(u16 u) {
  union { float f; uint32_t i; } v; v.i = ((uint32_t)u) << 16; return v.f;
}
__device__ __forceinline__ u16 f2bf(float f) {
  union { float f; uint32_t i; } v; v.f = f;
  uint32_t r = v.i + 0x7fffu + ((v.i >> 16) & 1u);
  return (u16)(r >> 16);
}
__device__ __forceinline__ floatx4 mfma16(short8 a, short8 b, floatx4 c) {
  return __builtin_amdgcn_mfma_f32_16x16x32_bf16(a, b, c, 0, 0, 0);
}

// ---------------- dtype detect: bf16 vs fp32 input arrays ------------------
__global__ void detect_k(const u16* __restrict__ xraw, int* __restrict__ flag) {
  int lane = threadIdx.x & 63;
  u16 w = xraw[lane * 2];
  int ex = (w >> 7) & 0xFF;
  bool hit = (ex >= 100 && ex <= 135);
  unsigned long long m = __ballot(hit);
  if (lane == 0) *flag = (__popcll(m) >= 40) ? 1 : 0;
}

// ---------------- alpha convert -> canonical bf16 --------------------------
__global__ void conv_alpha_k(const void* __restrict__ araw, u16* __restrict__ ab,
                             const int* __restrict__ flag) {
  int f = *flag;
  if (threadIdx.x < NE) {
    ab[threadIdx.x] = f ? ((const u16*)araw)[threadIdx.x]
                        : f2bf(((const float*)araw)[threadIdx.x]);
  }
}

// ---------------- x convert -> canonical bf16 (fp32 case only) -------------
__global__ __launch_bounds__(256) void conv_x_k(const void* __restrict__ xraw,
                                                u16* __restrict__ xb,
                                                const int* __restrict__ flag) {
  if (*flag) return;
  size_t base = ((size_t)blockIdx.x * 256 + threadIdx.x) * 8;
  const float* s = (const float*)xraw + base;
  float4 v0 = *(const float4*)s;
  float4 v1 = *(const float4*)(s + 4);
  ushort4 o0, o1;
  o0.x = f2bf(v0.x); o0.y = f2bf(v0.y); o0.z = f2bf(v0.z); o0.w = f2bf(v0.w);
  o1.x = f2bf(v1.x); o1.y = f2bf(v1.y); o1.z = f2bf(v1.z); o1.w = f2bf(v1.w);
  *(ushort4*)(xb + base) = o0;
  *(ushort4*)(xb + base + 4) = o1;
}

// ---------------- transpose+convert: src [E][R][C] -> dst bf16 [E][C][R] ---
__global__ __launch_bounds__(256) void transpose_k(
    const void* __restrict__ src, u16* __restrict__ dst, int R, int C,
    const u16* __restrict__ alphab, int mode, const int* __restrict__ flag) {
  int e = blockIdx.z;
  if (mode) {
    float a = bf2f(alphab[e]);
    if (mode == 1 && a == 1.0f) return;  // Wx unused when alpha==1
    if (mode == 2 && a == 0.0f) return;  // Wg unused when alpha==0
  }
  int f = *flag;
  __shared__ u16 tile[64][65];
  u16* d = dst + (size_t)e * R * C;
  int c0 = blockIdx.x * 64, r0 = blockIdx.y * 64;
  int tx = threadIdx.x & 63, ty = threadIdx.x >> 6;
  if (f) {
    const u16* s = (const u16*)src + (size_t)e * R * C;
    for (int i = ty; i < 64; i += 4)
      tile[i][tx] = s[(size_t)(r0 + i) * C + (c0 + tx)];
  } else {
    const float* s = (const float*)src + (size_t)e * R * C;
    for (int i = ty; i < 64; i += 4)
      tile[i][tx] = f2bf(s[(size_t)(r0 + i) * C + (c0 + tx)]);
  }
  __syncthreads();
  for (int i = ty; i < 64; i += 4)
    d[(size_t)(c0 + i) * R + (r0 + tx)] = tile[tx][i];
}

// ---------------- router phase 1: logits+softmax, NO atomics ---------------
__global__ __launch_bounds__(256) void rdot_k(
    const void* __restrict__ x, const void* __restrict__ Wr,
    float* __restrict__ probs, const int* __restrict__ flag) {
  int wave = threadIdx.x >> 6, lane = threadIdx.x & 63;
  int t = blockIdx.x * 4 + wave;
  int f = *flag;
  float acc[8];
  #pragma unroll
  for (int e = 0; e < 8; e++) acc[e] = 0.0f;
  if (f) {
    const u16* xr = (const u16*)x + (size_t)t * DM;
    const u16* wr = (const u16*)Wr;
    #pragma unroll
    for (int i = 0; i < 16; i++) {
      int d = i * 64 + lane;
      float xv = bf2f(xr[d]);
      uint4 wv = *(const uint4*)(wr + (size_t)d * 8);
      acc[0] += xv * bf2f((u16)(wv.x & 0xffff));
      acc[1] += xv * bf2f((u16)(wv.x >> 16));
      acc[2] += xv * bf2f((u16)(wv.y & 0xffff));
      acc[3] += xv * bf2f((u16)(wv.y >> 16));
      acc[4] += xv * bf2f((u16)(wv.z & 0xffff));
      acc[5] += xv * bf2f((u16)(wv.z >> 16));
      acc[6] += xv * bf2f((u16)(wv.w & 0xffff));
      acc[7] += xv * bf2f((u16)(wv.w >> 16));
    }
  } else {
    const float* xr = (const float*)x + (size_t)t * DM;
    const float* wr = (const float*)Wr;
    #pragma unroll
    for (int i = 0; i < 16; i++) {
      int d = i * 64 + lane;
      float xv = xr[d];
      float4 w0 = *(const float4*)(wr + (size_t)d * 8);
      float4 w1 = *(const float4*)(wr + (size_t)d * 8 + 4);
      acc[0] += xv * w0.x; acc[1] += xv * w0.y;
      acc[2] += xv * w0.z; acc[3] += xv * w0.w;
      acc[4] += xv * w1.x; acc[5] += xv * w1.y;
      acc[6] += xv * w1.z; acc[7] += xv * w1.w;
    }
  }
  #pragma unroll
  for (int e = 0; e < 8; e++) {
    #pragma unroll
    for (int s = 32; s; s >>= 1) acc[e] += __shfl_xor(acc[e], s, 64);
  }
  float mx = acc[0];
  #pragma unroll
  for (int e = 1; e < 8; e++) mx = fmaxf(mx, acc[e]);
  float p[8], sum = 0.0f;
  #pragma unroll
  for (int e = 0; e < 8; e++) { p[e] = __expf(acc[e] - mx); sum += p[e]; }
  float inv = 1.0f / sum;
  if (lane < 8) probs[(size_t)t * 8 + lane] = p[lane] * inv;
}

// ---------------- router phase 2: build expert lists (few atomics) ---------
__global__ __launch_bounds__(256) void build_k(
    const float* __restrict__ probs, int* __restrict__ counts,
    float* __restrict__ usage, int* __restrict__ tok_ids,
    float* __restrict__ tok_w) {
  __shared__ int sCnt[8];
  __shared__ int sBase[8];
  __shared__ float sUse[8];
  int tid = threadIdx.x;
  if (tid < 8) { sCnt[tid] = 0; sUse[tid] = 0.0f; }
  __syncthreads();

  int t = blockIdx.x * 256 + tid;
  float4 p0 = *(const float4*)(probs + (size_t)t * 8);
  float4 p1 = *(const float4*)(probs + (size_t)t * 8 + 4);
  float p[8] = {p0.x, p0.y, p0.z, p0.w, p1.x, p1.y, p1.z, p1.w};

  #pragma unroll
  for (int e = 0; e < 8; e++) {
    float v = p[e];
    #pragma unroll
    for (int s = 32; s; s >>= 1) v += __shfl_xor(v, s, 64);
    if ((tid & 63) == 0) atomicAdd(&sUse[e], v);
  }

  int e0 = 0;
  #pragma unroll
  for (int e = 1; e < 8; e++) if (p[e] > p[e0]) e0 = e;
  int e1 = (e0 == 0) ? 1 : 0;
  #pragma unroll
  for (int e = 0; e < 8; e++) if (e != e0 && p[e] > p[e1]) e1 = e;
  float s2 = 1.0f / (p[e0] + p[e1]);

  int s0 = atomicAdd(&sCnt[e0], 1);
  int s1 = atomicAdd(&sCnt[e1], 1);
  __syncthreads();
  if (tid < 8) {
    sBase[tid] = atomicAdd(&counts[tid], sCnt[tid]);
    atomicAdd(&usage[tid], sUse[tid]);
  }
  __syncthreads();
  int i0 = sBase[e0] + s0;
  tok_ids[e0 * T_TOK + i0] = t; tok_w[e0 * T_TOK + i0] = p[e0] * s2;
  int i1 = sBase[e1] + s1;
  tok_ids[e1 * T_TOK + i1] = t; tok_w[e1 * T_TOK + i1] = p[e1] * s2;
}

__global__ void scan_k(const int* __restrict__ counts, int* __restrict__ offs) {
  if (threadIdx.x == 0) {
    int s = 0;
    for (int e = 0; e < 8; e++) { offs[e] = s; s += counts[e]; }
    offs[8] = s;
  }
}

// ---------------- stage A: gathered x @ {Wg,Wu,Wx}^T, fused silu-combine ----
__global__ __launch_bounds__(256, 2) void stageA_k(
    const void* __restrict__ xraw, const u16* __restrict__ xb,
    const u16* __restrict__ WgT, const u16* __restrict__ WuT,
    const u16* __restrict__ WxT, const u16* __restrict__ alphab,
    const int* __restrict__ counts, const int* __restrict__ offs,
    const int* __restrict__ tok_ids, u16* __restrict__ comb,
    const int* __restrict__ flag) {
  int e = blockIdx.z;
  int cnt = counts[e];
  int m0 = blockIdx.y * 128;
  if (m0 >= cnt) return;
  int h0 = blockIdx.x * 64;
  int rem = cnt - m0;
  const u16* x = (*flag) ? (const u16*)xraw : xb;

  alignas(16) __shared__ u16 sA[128 * LDA];
  alignas(16) __shared__ u16 sG[64 * LDA];
  alignas(16) __shared__ u16 sU[64 * LDA];
  alignas(16) __shared__ u16 sX[64 * LDA];
  __shared__ int sTok[128];

  int tid = threadIdx.x;
  if (tid < 128)
    sTok[tid] = tok_ids[e * T_TOK + ((tid < rem) ? (m0 + tid) : m0)];
  __syncthreads();

  float aE = bf2f(alphab[e]);
  bool needG = (aE != 0.0f);
  bool needX = (aE != 1.0f);

  const u16* wg = WgT + (size_t)e * HD * DM;
  const u16* wu = WuT + (size_t)e * HD * DM;
  const u16* wx = WxT + (size_t)e * HD * DM;

  int lane = tid & 63, wave = tid >> 6;
  int wm = wave & 1, wn = wave >> 1;
  int lr = lane & 15, quad = lane >> 4;

  int rowA[4], segA[4], rowW[2], segW[2];
  #pragma unroll
  for (int i = 0; i < 4; i++) { int f = tid + 256 * i; rowA[i] = f >> 3; segA[i] = f & 7; }
  #pragma unroll
  for (int i = 0; i < 2; i++) { int f = tid + 256 * i; rowW[i] = f >> 3; segW[i] = f & 7; }

  floatx4 accG[4][2], accU[4][2], accX[4][2];
  #pragma unroll
  for (int i = 0; i < 4; i++)
    #pragma unroll
    for (int j = 0; j < 2; j++) {
      accG[i][j] = (floatx4)0.0f; accU[i][j] = (floatx4)0.0f; accX[i][j] = (floatx4)0.0f;
    }

  short8 rA[4], rU[2], rG[2], rX[2];
  #pragma unroll
  for (int i = 0; i < 4; i++)
    rA[i] = *(const short8*)(x + (size_t)sTok[rowA[i]] * DM + segA[i] * 8);
  #pragma unroll
  for (int i = 0; i < 2; i++) {
    size_t go = (size_t)(h0 + rowW[i]) * DM + segW[i] * 8;
    rU[i] = *(const short8*)(wu + go);
    if (needG) rG[i] = *(const short8*)(wg + go);
    if (needX) rX[i] = *(const short8*)(wx + go);
  }

  const int NK = DM / 64;
  for (int kt = 0; kt < NK; kt++) {
    __syncthreads();
    #pragma unroll
    for (int i = 0; i < 4; i++)
      *(short8*)&sA[rowA[i] * LDA + segA[i] * 8] = rA[i];
    #pragma unroll
    for (int i = 0; i < 2; i++) {
      *(short8*)&sU[rowW[i] * LDA + segW[i] * 8] = rU[i];
      if (needG) *(short8*)&sG[rowW[i] * LDA + segW[i] * 8] = rG[i];
      if (needX) *(short8*)&sX[rowW[i] * LDA + segW[i] * 8] = rX[i];
    }
    __syncthreads();
    if (kt + 1 < NK) {
      int k0 = (kt + 1) * 64;
      #pragma unroll
      for (int i = 0; i < 4; i++)
        rA[i] = *(const short8*)(x + (size_t)sTok[rowA[i]] * DM + k0 + segA[i] * 8);
      #pragma unroll
      for (int i = 0; i < 2; i++) {
        size_t go = (size_t)(h0 + rowW[i]) * DM + k0 + segW[i] * 8;
        rU[i] = *(const short8*)(wu + go);
        if (needG) rG[i] = *(const short8*)(wg + go);
        if (needX) rX[i] = *(const short8*)(wx + go);
      }
    }
    #pragma unroll
    for (int kk = 0; kk < 2; kk++) {
      int kb = kk * 32 + quad * 8;
      short8 a[4];
      #pragma unroll
      for (int i = 0; i < 4; i++)
        a[i] = *(const short8*)&sA[(wm * 64 + i * 16 + lr) * LDA + kb];
      #pragma unroll
      for (int j = 0; j < 2; j++) {
        int nb = (wn * 32 + j * 16 + lr) * LDA + kb;
        short8 bu = *(const short8*)&sU[nb];
        #pragma unroll
        for (int i = 0; i < 4; i++) accU[i][j] = mfma16(a[i], bu, accU[i][j]);
        if (needG) {
          short8 bg = *(const short8*)&sG[nb];
          #pragma unroll
          for (int i = 0; i < 4; i++) accG[i][j] = mfma16(a[i], bg, accG[i][j]);
        }
        if (needX) {
          short8 bx = *(const short8*)&sX[nb];
          #pragma unroll
          for (int i = 0; i < 4; i++) accX[i][j] = mfma16(a[i], bx, accX[i][j]);
        }
      }
    }
  }

  float a1 = aE, a2 = 1.0f - aE;
  size_t rbase = (size_t)(offs[e] + m0);
  #pragma unroll
  for (int i = 0; i < 4; i++) {
    #pragma unroll
    for (int r = 0; r < 4; r++) {
      int row = wm * 64 + i * 16 + quad * 4 + r;
      if (row < rem) {
        u16* cp = comb + (rbase + row) * HD + h0 + wn * 32 + lr;
        #pragma unroll
        for (int j = 0; j < 2; j++) {
          float g = accG[i][j][r], u = accU[i][j][r], xx = accX[i][j][r];
          float sg = g / (1.0f + __expf(-g));
          float sx = xx / (1.0f + __expf(-xx));
          cp[j * 16] = f2bf(u * (a1 * sg + a2 * sx));
        }
      }
    }
  }
}

// ---------------- stage B: combined @ WdT, scaled scatter-accumulate -------
__global__ __launch_bounds__(256, 2) void stageB_k(
    const u16* __restrict__ comb, const u16* __restrict__ WdT,
    const int* __restrict__ counts, const int* __restrict__ offs,
    const int* __restrict__ tok_ids, const float* __restrict__ tok_w,
    float* __restrict__ accb) {
  int e = blockIdx.z;
  int cnt = counts[e];
  int m0 = blockIdx.y * 128;
  if (m0 >= cnt) return;
  int d0 = blockIdx.x * 128;
  int rem = cnt - m0;

  alignas(16) __shared__ u16 sA[128 * LDA];
  alignas(16) __shared__ u16 sB[128 * LDA];
  __shared__ int sTok[128];
  __shared__ float sW[128];

  int tid = threadIdx.x;
  if (tid < 128) {
    bool v = tid < rem;
    sTok[tid] = v ? tok_ids[e * T_TOK + m0 + tid] : 0;
    sW[tid] = v ? tok_w[e * T_TOK + m0 + tid] : 0.0f;
  }
  __syncthreads();

  const u16* ca = comb + (size_t)(offs[e] + m0) * HD;
  const u16* wd = WdT + (size_t)e * DM * HD;

  int lane = tid & 63, wave = tid >> 6;
  int wm = wave & 1, wn = wave >> 1;
  int lr = lane & 15, quad = lane >> 4;

  int rowS[4], segS[4], rowC[4];
  #pragma unroll
  for (int i = 0; i < 4; i++) {
    int f = tid + 256 * i;
    rowS[i] = f >> 3; segS[i] = f & 7;
    rowC[i] = (rowS[i] < rem) ? rowS[i] : 0;
  }

  floatx4 acc[4][4];
  #pragma unroll
  for (int i = 0; i < 4; i++)
    #pragma unroll
    for (int j = 0; j < 4; j++) acc[i][j] = (floatx4)0.0f;

  short8 rAr[4], rBr[4];
  #pragma unroll
  for (int i = 0; i < 4; i++) {
    rAr[i] = *(const short8*)(ca + (size_t)rowC[i] * HD + segS[i] * 8);
    rBr[i] = *(const short8*)(wd + (size_t)(d0 + rowS[i]) * HD + segS[i] * 8);
  }

  const int NK = HD / 64;
  for (int kt = 0; kt < NK; kt++) {
    __syncthreads();
    #pragma unroll
    for (int i = 0; i < 4; i++) {
      *(short8*)&sA[rowS[i] * LDA + segS[i] * 8] = rAr[i];
      *(short8*)&sB[rowS[i] * LDA + segS[i] * 8] = rBr[i];
    }
    __syncthreads();
    if (kt + 1 < NK) {
      int k0 = (kt + 1) * 64;
      #pragma unroll
      for (int i = 0; i < 4; i++) {
        rAr[i] = *(const short8*)(ca + (size_t)rowC[i] * HD + k0 + segS[i] * 8);
        rBr[i] = *(const short8*)(wd + (size_t)(d0 + rowS[i]) * HD + k0 + segS[i] * 8);
      }
    }
    #pragma unroll
    for (int kk = 0; kk < 2; kk++) {
      int kb = kk * 32 + quad * 8;
      short8 a[4];
      #pragma unroll
      for (int i = 0; i < 4; i++)
        a[i] = *(const short8*)&sA[(wm * 64 + i * 16 + lr) * LDA + kb];
      #pragma unroll
      for (int j = 0; j < 4; j++) {
        short8 b = *(const short8*)&sB[(wn * 64 + j * 16 + lr) * LDA + kb];
        #pragma unroll
        for (int i = 0; i < 4; i++) acc[i][j] = mfma16(a[i], b, acc[i][j]);
      }
    }
  }

  #pragma unroll
  for (int i = 0; i < 4; i++) {
    #pragma unroll
    for (int r = 0; r < 4; r++) {
      int row = wm * 64 + i * 16 + quad * 4 + r;
      if (row < rem) {
        int t = sTok[row];
        float w = sW[row];
        float* orow = accb + (size_t)t * DM + d0 + wn * 64 + lr;
        #pragma unroll
        for (int j = 0; j < 4; j++)
          atomicAdd(&orow[j * 16], acc[i][j][r] * w);
      }
    }
  }
}

// ---------------- finalize: fp32 accum -> out (dual dtype), lb scalar ------
__global__ __launch_bounds__(256) void finalize_k(
    const float* __restrict__ accb, const float* __restrict__ usage,
    void* __restrict__ out, const int* __restrict__ flag) {
  int f = *flag;
  size_t idx = (size_t)blockIdx.x * 256 + threadIdx.x;
  float4 v = ((const float4*)accb)[idx];
  float lb = 0.0f;
  if (idx == 0) {
    for (int e = 0; e < 8; e++) {
      float d = usage[e] * (1.0f / 8192.0f) - 0.125f;
      lb += d * d;
    }
    lb *= 0.01f * 0.125f;
  }
  if (f) {
    u16* o = (u16*)out;
    ushort4 ov;
    ov.x = f2bf(v.x); ov.y = f2bf(v.y); ov.z = f2bf(v.z); ov.w = f2bf(v.w);
    ((ushort4*)o)[idx] = ov;
    if (idx == 0) o[(size_t)T_TOK * DM] = f2bf(lb);
  } else {
    float* o = (float*)out;
    ((float4*)o)[idx] = v;
    if (idx == 0) o[(size_t)T_TOK * DM] = lb;
  }
}

extern "C" void kernel_launch(void* const* d_in, const int* in_sizes, int n_in,
                              void* d_out, int out_size, void* d_ws, size_t ws_size,
                              hipStream_t stream) {
  const void* x  = d_in[0];
  const void* Wr = d_in[1];
  const void* Wg = d_in[2];
  const void* Wu = d_in[3];
  const void* Wx = d_in[4];
  const void* Wd = d_in[5];
  const void* al = d_in[6];
  char* ws = (char*)d_ws;

  int*   counts  = (int*)(ws + 0);           // 32
  float* usage   = (float*)(ws + 32);        // 32
  int*   flag    = (int*)(ws + 64);          // pad to 128
  float* accb    = (float*)(ws + 128);       // 33,554,432
  int*   offs    = (int*)(ws + 33554560);    // 64
  int*   tok_ids = (int*)(ws + 33554624);    // 262,144
  float* tok_w   = (float*)(ws + 33816768);  // 262,144
  u16*   alphab  = (u16*)(ws + 34078912);    // 64
  u16*   xb      = (u16*)(ws + 34078976);    // 16,777,216
  u16*   comb    = (u16*)(ws + 50856192);    // 46,137,344
  u16*   WgT     = (u16*)(ws + 96993536);    // 23,068,672
  u16*   WuT     = (u16*)(ws + 120062208);   // 23,068,672
  u16*   WdT     = (u16*)(ws + 143130880);   // 23,068,672
  float* probs   = (float*)(ws + 166199552); // 262,144
  u16*   WxT     = (u16*)(ws + 166461696);   // 23,068,672 (touched only if alpha!=1)

  hipMemsetAsync(ws, 0, 33554560, stream);  // counts+usage+flag+accb

  dim3 b256(256, 1, 1);
  detect_k<<<dim3(1), dim3(64), 0, stream>>>((const u16*)x, flag);
  conv_alpha_k<<<dim3(1), dim3(64), 0, stream>>>(al, alphab, flag);
  conv_x_k<<<dim3(4096), b256, 0, stream>>>(x, xb, flag);
  transpose_k<<<dim3(HD / 64, DM / 64, NE), b256, 0, stream>>>(Wg, WgT, DM, HD, alphab, 2, flag);
  transpose_k<<<dim3(HD / 64, DM / 64, NE), b256, 0, stream>>>(Wu, WuT, DM, HD, alphab, 0, flag);
  transpose_k<<<dim3(HD / 64, DM / 64, NE), b256, 0, stream>>>(Wx, WxT, DM, HD, alphab, 1, flag);
  transpose_k<<<dim3(DM / 64, HD / 64, NE), b256, 0, stream>>>(Wd, WdT, HD, DM, alphab, 0, flag);
  rdot_k<<<dim3(T_TOK / 4), b256, 0, stream>>>(x, Wr, probs, flag);
  build_k<<<dim3(T_TOK / 256), b256, 0, stream>>>(probs, counts, usage, tok_ids, tok_w);
  scan_k<<<dim3(1), dim3(64), 0, stream>>>(counts, offs);
  stageA_k<<<dim3(HD / 64, T_TOK / 128, NE), b256, 0, stream>>>(
      x, xb, WgT, WuT, WxT, alphab, counts, offs, tok_ids, comb, flag);
  stageB_k<<<dim3(DM / 128, T_TOK / 128, NE), b256, 0, stream>>>(
      comb, WdT, counts, offs, tok_ids, tok_w, accb);
  finalize_k<<<dim3((T_TOK * DM / 4) / 256), b256, 0, stream>>>(accb, usage, d_out, flag);
}

// Round 6
// 508.554 us; speedup vs baseline: 1.4851x; 1.0240x over previous
//
#include <hip/hip_runtime.h>
#include <stdint.h>

typedef unsigned short u16;
typedef __attribute__((ext_vector_type(8))) short short8;
typedef __attribute__((ext_vector_type(4))) float floatx4;

#define T_TOK 8192
#define DM 1024
#define NE 8
#define HD 1408
#define LDA 72  // padded stride for the fallback (register-staged) kernel only

__device__ __forceinline__ float bf2f(u16 u) {
  union { float f; uint32_t i; } v; v.i = ((uint32_t)u) << 16; return v.f;
}
__device__ __forceinline__ u16 f2bf(float f) {
  union { float f; uint32_t i; } v; v.f = f;
  uint32_t r = v.i + 0x7fffu + ((v.i >> 16) & 1u);
  return (u16)(r >> 16);
}
__device__ __forceinline__ void llds16(const void* g, void* l) {
  __builtin_amdgcn_global_load_lds((const __attribute__((address_space(1))) void*)g,
                                   (__attribute__((address_space(3))) void*)l, 16, 0, 0);
}
__device__ __forceinline__ floatx4 mfma16(short8 a, short8 b, floatx4 c) {
  return __builtin_amdgcn_mfma_f32_16x16x32_bf16(a, b, c, 0, 0, 0);
}

// ---------------- dtype detect: bf16 vs fp32 input arrays ------------------
__global__ void detect_k(const u16* __restrict__ xraw, int* __restrict__ flag) {
  int lane = threadIdx.x & 63;
  u16 w = xraw[lane * 2];
  int ex = (w >> 7) & 0xFF;
  bool hit = (ex >= 100 && ex <= 135);
  unsigned long long m = __ballot(hit);
  if (lane == 0) *flag = (__popcll(m) >= 40) ? 1 : 0;
}

// ---------------- alpha convert -> canonical bf16 --------------------------
__global__ void conv_alpha_k(const void* __restrict__ araw, u16* __restrict__ ab,
                             const int* __restrict__ flag) {
  int f = *flag;
  if (threadIdx.x < NE) {
    ab[threadIdx.x] = f ? ((const u16*)araw)[threadIdx.x]
                        : f2bf(((const float*)araw)[threadIdx.x]);
  }
}

// ---------------- x convert -> canonical bf16 (fp32 case only) -------------
__global__ __launch_bounds__(256) void conv_x_k(const void* __restrict__ xraw,
                                                u16* __restrict__ xb,
                                                const int* __restrict__ flag) {
  if (*flag) return;
  size_t base = ((size_t)blockIdx.x * 256 + threadIdx.x) * 8;
  const float* s = (const float*)xraw + base;
  float4 v0 = *(const float4*)s;
  float4 v1 = *(const float4*)(s + 4);
  ushort4 o0, o1;
  o0.x = f2bf(v0.x); o0.y = f2bf(v0.y); o0.z = f2bf(v0.z); o0.w = f2bf(v0.w);
  o1.x = f2bf(v1.x); o1.y = f2bf(v1.y); o1.z = f2bf(v1.z); o1.w = f2bf(v1.w);
  *(ushort4*)(xb + base) = o0;
  *(ushort4*)(xb + base + 4) = o1;
}

// ---------------- transpose+convert: src [E][R][C] -> dst bf16 [E][C][R] ---
__global__ __launch_bounds__(256) void transpose_k(
    const void* __restrict__ src, u16* __restrict__ dst, int R, int C,
    const u16* __restrict__ alphab, int mode, const int* __restrict__ flag) {
  int e = blockIdx.z;
  if (mode) {
    float a = bf2f(alphab[e]);
    if (mode == 1 && a == 1.0f) return;  // Wx unused when alpha==1
    if (mode == 2 && a == 0.0f) return;  // Wg unused when alpha==0
  }
  int f = *flag;
  __shared__ u16 tile[64][65];
  u16* d = dst + (size_t)e * R * C;
  int c0 = blockIdx.x * 64, r0 = blockIdx.y * 64;
  int tx = threadIdx.x & 63, ty = threadIdx.x >> 6;
  if (f) {
    const u16* s = (const u16*)src + (size_t)e * R * C;
    for (int i = ty; i < 64; i += 4)
      tile[i][tx] = s[(size_t)(r0 + i) * C + (c0 + tx)];
  } else {
    const float* s = (const float*)src + (size_t)e * R * C;
    for (int i = ty; i < 64; i += 4)
      tile[i][tx] = f2bf(s[(size_t)(r0 + i) * C + (c0 + tx)]);
  }
  __syncthreads();
  int i2 = threadIdx.x >> 5, tx2 = threadIdx.x & 31;
  for (int ii = i2; ii < 64; ii += 8) {
    ushort2 v; v.x = tile[2 * tx2][ii]; v.y = tile[2 * tx2 + 1][ii];
    *(ushort2*)&d[(size_t)(c0 + ii) * R + r0 + 2 * tx2] = v;
  }
}

// ---------------- router phase 1: logits+softmax, NO atomics ---------------
__global__ __launch_bounds__(256) void rdot_k(
    const void* __restrict__ x, const void* __restrict__ Wr,
    float* __restrict__ probs, const int* __restrict__ flag) {
  int wave = threadIdx.x >> 6, lane = threadIdx.x & 63;
  int t = blockIdx.x * 4 + wave;
  int f = *flag;
  float acc[8];
  #pragma unroll
  for (int e = 0; e < 8; e++) acc[e] = 0.0f;
  if (f) {
    const u16* xr = (const u16*)x + (size_t)t * DM;
    const u16* wr = (const u16*)Wr;
    #pragma unroll
    for (int i = 0; i < 16; i++) {
      int d = i * 64 + lane;
      float xv = bf2f(xr[d]);
      uint4 wv = *(const uint4*)(wr + (size_t)d * 8);
      acc[0] += xv * bf2f((u16)(wv.x & 0xffff));
      acc[1] += xv * bf2f((u16)(wv.x >> 16));
      acc[2] += xv * bf2f((u16)(wv.y & 0xffff));
      acc[3] += xv * bf2f((u16)(wv.y >> 16));
      acc[4] += xv * bf2f((u16)(wv.z & 0xffff));
      acc[5] += xv * bf2f((u16)(wv.z >> 16));
      acc[6] += xv * bf2f((u16)(wv.w & 0xffff));
      acc[7] += xv * bf2f((u16)(wv.w >> 16));
    }
  } else {
    const float* xr = (const float*)x + (size_t)t * DM;
    const float* wr = (const float*)Wr;
    #pragma unroll
    for (int i = 0; i < 16; i++) {
      int d = i * 64 + lane;
      float xv = xr[d];
      float4 w0 = *(const float4*)(wr + (size_t)d * 8);
      float4 w1 = *(const float4*)(wr + (size_t)d * 8 + 4);
      acc[0] += xv * w0.x; acc[1] += xv * w0.y;
      acc[2] += xv * w0.z; acc[3] += xv * w0.w;
      acc[4] += xv * w1.x; acc[5] += xv * w1.y;
      acc[6] += xv * w1.z; acc[7] += xv * w1.w;
    }
  }
  #pragma unroll
  for (int e = 0; e < 8; e++) {
    #pragma unroll
    for (int s = 32; s; s >>= 1) acc[e] += __shfl_xor(acc[e], s, 64);
  }
  float mx = acc[0];
  #pragma unroll
  for (int e = 1; e < 8; e++) mx = fmaxf(mx, acc[e]);
  float p[8], sum = 0.0f;
  #pragma unroll
  for (int e = 0; e < 8; e++) { p[e] = __expf(acc[e] - mx); sum += p[e]; }
  float inv = 1.0f / sum;
  if (lane < 8) probs[(size_t)t * 8 + lane] = p[lane] * inv;
}

// ---------------- router phase 2: build expert lists (few atomics) ---------
__global__ __launch_bounds__(256) void build_k(
    const float* __restrict__ probs, int* __restrict__ counts,
    float* __restrict__ usage, int* __restrict__ tok_ids,
    float* __restrict__ tok_w) {
  __shared__ int sCnt[8];
  __shared__ int sBase[8];
  __shared__ float sUse[8];
  int tid = threadIdx.x;
  if (tid < 8) { sCnt[tid] = 0; sUse[tid] = 0.0f; }
  __syncthreads();

  int t = blockIdx.x * 256 + tid;
  float4 p0 = *(const float4*)(probs + (size_t)t * 8);
  float4 p1 = *(const float4*)(probs + (size_t)t * 8 + 4);
  float p[8] = {p0.x, p0.y, p0.z, p0.w, p1.x, p1.y, p1.z, p1.w};

  #pragma unroll
  for (int e = 0; e < 8; e++) {
    float v = p[e];
    #pragma unroll
    for (int s = 32; s; s >>= 1) v += __shfl_xor(v, s, 64);
    if ((tid & 63) == 0) atomicAdd(&sUse[e], v);
  }

  int e0 = 0;
  #pragma unroll
  for (int e = 1; e < 8; e++) if (p[e] > p[e0]) e0 = e;
  int e1 = (e0 == 0) ? 1 : 0;
  #pragma unroll
  for (int e = 0; e < 8; e++) if (e != e0 && p[e] > p[e1]) e1 = e;
  float s2 = 1.0f / (p[e0] + p[e1]);

  int s0 = atomicAdd(&sCnt[e0], 1);
  int s1 = atomicAdd(&sCnt[e1], 1);
  __syncthreads();
  if (tid < 8) {
    sBase[tid] = atomicAdd(&counts[tid], sCnt[tid]);
    atomicAdd(&usage[tid], sUse[tid]);
  }
  __syncthreads();
  int i0 = sBase[e0] + s0;
  tok_ids[e0 * T_TOK + i0] = t; tok_w[e0 * T_TOK + i0] = p[e0] * s2;
  int i1 = sBase[e1] + s1;
  tok_ids[e1 * T_TOK + i1] = t; tok_w[e1 * T_TOK + i1] = p[e1] * s2;
}

__global__ void scan_k(const int* __restrict__ counts, int* __restrict__ offs) {
  if (threadIdx.x == 0) {
    int s = 0;
    for (int e = 0; e < 8; e++) { offs[e] = s; s += counts[e]; }
    offs[8] = s;
  }
}

// ---------------- stage A lean (alpha==1): async-staged, BN=128 ------------
// combined = silu(x@Wg) * (x@Wu). global_load_lds width=16, unpadded LDS.
__global__ __launch_bounds__(256, 2) void stageA2_k(
    const void* __restrict__ xraw, const u16* __restrict__ xb,
    const u16* __restrict__ WgT, const u16* __restrict__ WuT,
    const u16* __restrict__ alphab, const int* __restrict__ counts,
    const int* __restrict__ offs, const int* __restrict__ tok_ids,
    u16* __restrict__ comb, const int* __restrict__ flag) {
  int e = blockIdx.z;
  float aE = bf2f(alphab[e]);
  if (aE != 1.0f) return;  // fallback kernel handles alpha != 1
  int cnt = counts[e];
  int m0 = blockIdx.y * 128;
  if (m0 >= cnt) return;
  int h0 = blockIdx.x * 128;
  int rem = cnt - m0;
  const u16* x = (*flag) ? (const u16*)xraw : xb;

  alignas(16) __shared__ u16 sA[128 * 64];
  alignas(16) __shared__ u16 sG[128 * 64];
  alignas(16) __shared__ u16 sU[128 * 64];
  __shared__ int sTok[128];

  int tid = threadIdx.x;
  if (tid < 128)
    sTok[tid] = tok_ids[e * T_TOK + ((tid < rem) ? (m0 + tid) : m0)];
  __syncthreads();

  const u16* wg = WgT + (size_t)e * HD * DM;
  const u16* wu = WuT + (size_t)e * HD * DM;

  int lane = tid & 63, wave = tid >> 6;
  int wm = wave & 1, wn = wave >> 1;
  int lr = lane & 15, quad = lane >> 4;

  // fixed per-thread staging coordinates and hoisted pointers
  const u16* aptr[4]; const u16* gptr[4]; const u16* uptr[4];
  u16 *dA[4], *dG[4], *dU[4];
  #pragma unroll
  for (int i = 0; i < 4; i++) {
    int f = tid + 256 * i;
    int row = f >> 3, seg = f & 7;
    aptr[i] = x + (size_t)sTok[row] * DM + seg * 8;
    gptr[i] = wg + (size_t)(h0 + row) * DM + seg * 8;
    uptr[i] = wu + (size_t)(h0 + row) * DM + seg * 8;
    dA[i] = &sA[f * 8]; dG[i] = &sG[f * 8]; dU[i] = &sU[f * 8];
  }

  floatx4 accG[4][4], accU[4][4];
  #pragma unroll
  for (int i = 0; i < 4; i++)
    #pragma unroll
    for (int j = 0; j < 4; j++) { accG[i][j] = (floatx4)0.0f; accU[i][j] = (floatx4)0.0f; }

  for (int kt = 0; kt < DM / 64; kt++) {
    int k0 = kt * 64;
    __syncthreads();
    #pragma unroll
    for (int i = 0; i < 4; i++) llds16(aptr[i] + k0, dA[i]);
    #pragma unroll
    for (int i = 0; i < 4; i++) llds16(uptr[i] + k0, dU[i]);
    #pragma unroll
    for (int i = 0; i < 4; i++) llds16(gptr[i] + k0, dG[i]);
    __syncthreads();
    #pragma unroll
    for (int kk = 0; kk < 2; kk++) {
      int kb = kk * 32 + quad * 8;
      short8 a[4];
      #pragma unroll
      for (int i = 0; i < 4; i++)
        a[i] = *(const short8*)&sA[(wm * 64 + i * 16 + lr) * 64 + kb];
      #pragma unroll
      for (int j = 0; j < 4; j++) {
        int nb = (wn * 64 + j * 16 + lr) * 64 + kb;
        short8 bu = *(const short8*)&sU[nb];
        #pragma unroll
        for (int i = 0; i < 4; i++) accU[i][j] = mfma16(a[i], bu, accU[i][j]);
        short8 bg = *(const short8*)&sG[nb];
        #pragma unroll
        for (int i = 0; i < 4; i++) accG[i][j] = mfma16(a[i], bg, accG[i][j]);
      }
    }
  }

  size_t rbase = (size_t)(offs[e] + m0);
  #pragma unroll
  for (int i = 0; i < 4; i++) {
    #pragma unroll
    for (int r = 0; r < 4; r++) {
      int row = wm * 64 + i * 16 + quad * 4 + r;
      if (row < rem) {
        u16* cp = comb + (rbase + row) * HD + h0 + wn * 64 + lr;
        #pragma unroll
        for (int j = 0; j < 4; j++) {
          float g = accG[i][j][r], u = accU[i][j][r];
          float sg = g / (1.0f + __expf(-g));
          cp[j * 16] = f2bf(u * sg);
        }
      }
    }
  }
}

// ---------------- stage A fallback (alpha != 1): register-staged, BN=64 ----
__global__ __launch_bounds__(256, 2) void stageA_k(
    const void* __restrict__ xraw, const u16* __restrict__ xb,
    const u16* __restrict__ WgT, const u16* __restrict__ WuT,
    const u16* __restrict__ WxT, const u16* __restrict__ alphab,
    const int* __restrict__ counts, const int* __restrict__ offs,
    const int* __restrict__ tok_ids, u16* __restrict__ comb,
    const int* __restrict__ flag) {
  int e = blockIdx.z;
  float aE = bf2f(alphab[e]);
  if (aE == 1.0f) return;  // lean kernel handles alpha == 1
  int cnt = counts[e];
  int m0 = blockIdx.y * 128;
  if (m0 >= cnt) return;
  int h0 = blockIdx.x * 64;
  int rem = cnt - m0;
  const u16* x = (*flag) ? (const u16*)xraw : xb;

  alignas(16) __shared__ u16 sA[128 * LDA];
  alignas(16) __shared__ u16 sG[64 * LDA];
  alignas(16) __shared__ u16 sU[64 * LDA];
  alignas(16) __shared__ u16 sX[64 * LDA];
  __shared__ int sTok[128];

  int tid = threadIdx.x;
  if (tid < 128)
    sTok[tid] = tok_ids[e * T_TOK + ((tid < rem) ? (m0 + tid) : m0)];
  __syncthreads();

  bool needG = (aE != 0.0f);

  const u16* wg = WgT + (size_t)e * HD * DM;
  const u16* wu = WuT + (size_t)e * HD * DM;
  const u16* wx = WxT + (size_t)e * HD * DM;

  int lane = tid & 63, wave = tid >> 6;
  int wm = wave & 1, wn = wave >> 1;
  int lr = lane & 15, quad = lane >> 4;

  int rowA[4], segA[4], rowW[2], segW[2];
  #pragma unroll
  for (int i = 0; i < 4; i++) { int f = tid + 256 * i; rowA[i] = f >> 3; segA[i] = f & 7; }
  #pragma unroll
  for (int i = 0; i < 2; i++) { int f = tid + 256 * i; rowW[i] = f >> 3; segW[i] = f & 7; }

  floatx4 accG[4][2], accU[4][2], accX[4][2];
  #pragma unroll
  for (int i = 0; i < 4; i++)
    #pragma unroll
    for (int j = 0; j < 2; j++) {
      accG[i][j] = (floatx4)0.0f; accU[i][j] = (floatx4)0.0f; accX[i][j] = (floatx4)0.0f;
    }

  short8 rA[4], rU[2], rG[2], rX[2];
  #pragma unroll
  for (int i = 0; i < 4; i++)
    rA[i] = *(const short8*)(x + (size_t)sTok[rowA[i]] * DM + segA[i] * 8);
  #pragma unroll
  for (int i = 0; i < 2; i++) {
    size_t go = (size_t)(h0 + rowW[i]) * DM + segW[i] * 8;
    rU[i] = *(const short8*)(wu + go);
    if (needG) rG[i] = *(const short8*)(wg + go);
    rX[i] = *(const short8*)(wx + go);
  }

  const int NK = DM / 64;
  for (int kt = 0; kt < NK; kt++) {
    __syncthreads();
    #pragma unroll
    for (int i = 0; i < 4; i++)
      *(short8*)&sA[rowA[i] * LDA + segA[i] * 8] = rA[i];
    #pragma unroll
    for (int i = 0; i < 2; i++) {
      *(short8*)&sU[rowW[i] * LDA + segW[i] * 8] = rU[i];
      if (needG) *(short8*)&sG[rowW[i] * LDA + segW[i] * 8] = rG[i];
      *(short8*)&sX[rowW[i] * LDA + segW[i] * 8] = rX[i];
    }
    __syncthreads();
    if (kt + 1 < NK) {
      int k0 = (kt + 1) * 64;
      #pragma unroll
      for (int i = 0; i < 4; i++)
        rA[i] = *(const short8*)(x + (size_t)sTok[rowA[i]] * DM + k0 + segA[i] * 8);
      #pragma unroll
      for (int i = 0; i < 2; i++) {
        size_t go = (size_t)(h0 + rowW[i]) * DM + k0 + segW[i] * 8;
        rU[i] = *(const short8*)(wu + go);
        if (needG) rG[i] = *(const short8*)(wg + go);
        rX[i] = *(const short8*)(wx + go);
      }
    }
    #pragma unroll
    for (int kk = 0; kk < 2; kk++) {
      int kb = kk * 32 + quad * 8;
      short8 a[4];
      #pragma unroll
      for (int i = 0; i < 4; i++)
        a[i] = *(const short8*)&sA[(wm * 64 + i * 16 + lr) * LDA + kb];
      #pragma unroll
      for (int j = 0; j < 2; j++) {
        int nb = (wn * 32 + j * 16 + lr) * LDA + kb;
        short8 bu = *(const short8*)&sU[nb];
        #pragma unroll
        for (int i = 0; i < 4; i++) accU[i][j] = mfma16(a[i], bu, accU[i][j]);
        if (needG) {
          short8 bg = *(const short8*)&sG[nb];
          #pragma unroll
          for (int i = 0; i < 4; i++) accG[i][j] = mfma16(a[i], bg, accG[i][j]);
        }
        short8 bx = *(const short8*)&sX[nb];
        #pragma unroll
        for (int i = 0; i < 4; i++) accX[i][j] = mfma16(a[i], bx, accX[i][j]);
      }
    }
  }

  float a1 = aE, a2 = 1.0f - aE;
  size_t rbase = (size_t)(offs[e] + m0);
  #pragma unroll
  for (int i = 0; i < 4; i++) {
    #pragma unroll
    for (int r = 0; r < 4; r++) {
      int row = wm * 64 + i * 16 + quad * 4 + r;
      if (row < rem) {
        u16* cp = comb + (rbase + row) * HD + h0 + wn * 32 + lr;
        #pragma unroll
        for (int j = 0; j < 2; j++) {
          float g = accG[i][j][r], u = accU[i][j][r], xx = accX[i][j][r];
          float sg = g / (1.0f + __expf(-g));
          float sx = xx / (1.0f + __expf(-xx));
          cp[j * 16] = f2bf(u * (a1 * sg + a2 * sx));
        }
      }
    }
  }
}

// ---------------- stage B: combined @ WdT, async-staged --------------------
__global__ __launch_bounds__(256, 2) void stageB_k(
    const u16* __restrict__ comb, const u16* __restrict__ WdT,
    const int* __restrict__ counts, const int* __restrict__ offs,
    const int* __restrict__ tok_ids, const float* __restrict__ tok_w,
    float* __restrict__ accb) {
  int e = blockIdx.z;
  int cnt = counts[e];
  int m0 = blockIdx.y * 128;
  if (m0 >= cnt) return;
  int d0 = blockIdx.x * 128;
  int rem = cnt - m0;

  alignas(16) __shared__ u16 sA[128 * 64];
  alignas(16) __shared__ u16 sB[128 * 64];
  __shared__ int sTok[128];
  __shared__ float sW[128];

  int tid = threadIdx.x;
  if (tid < 128) {
    bool v = tid < rem;
    sTok[tid] = v ? tok_ids[e * T_TOK + m0 + tid] : 0;
    sW[tid] = v ? tok_w[e * T_TOK + m0 + tid] : 0.0f;
  }
  __syncthreads();

  const u16* ca = comb + (size_t)(offs[e] + m0) * HD;
  const u16* wd = WdT + (size_t)e * DM * HD;

  int lane = tid & 63, wave = tid >> 6;
  int wm = wave & 1, wn = wave >> 1;
  int lr = lane & 15, quad = lane >> 4;

  const u16* aptr[4]; const u16* bptr[4];
  u16 *dA[4], *dB[4];
  #pragma unroll
  for (int i = 0; i < 4; i++) {
    int f = tid + 256 * i;
    int row = f >> 3, seg = f & 7;
    int rc = (row < rem) ? row : 0;
    aptr[i] = ca + (size_t)rc * HD + seg * 8;
    bptr[i] = wd + (size_t)(d0 + row) * HD + seg * 8;
    dA[i] = &sA[f * 8]; dB[i] = &sB[f * 8];
  }

  floatx4 acc[4][4];
  #pragma unroll
  for (int i = 0; i < 4; i++)
    #pragma unroll
    for (int j = 0; j < 4; j++) acc[i][j] = (floatx4)0.0f;

  for (int kt = 0; kt < HD / 64; kt++) {
    int k0 = kt * 64;
    __syncthreads();
    #pragma unroll
    for (int i = 0; i < 4; i++) llds16(aptr[i] + k0, dA[i]);
    #pragma unroll
    for (int i = 0; i < 4; i++) llds16(bptr[i] + k0, dB[i]);
    __syncthreads();
    #pragma unroll
    for (int kk = 0; kk < 2; kk++) {
      int kb = kk * 32 + quad * 8;
      short8 a[4];
      #pragma unroll
      for (int i = 0; i < 4; i++)
        a[i] = *(const short8*)&sA[(wm * 64 + i * 16 + lr) * 64 + kb];
      #pragma unroll
      for (int j = 0; j < 4; j++) {
        short8 b = *(const short8*)&sB[(wn * 64 + j * 16 + lr) * 64 + kb];
        #pragma unroll
        for (int i = 0; i < 4; i++) acc[i][j] = mfma16(a[i], b, acc[i][j]);
      }
    }
  }

  #pragma unroll
  for (int i = 0; i < 4; i++) {
    #pragma unroll
    for (int r = 0; r < 4; r++) {
      int row = wm * 64 + i * 16 + quad * 4 + r;
      if (row < rem) {
        int t = sTok[row];
        float w = sW[row];
        float* orow = accb + (size_t)t * DM + d0 + wn * 64 + lr;
        #pragma unroll
        for (int j = 0; j < 4; j++)
          atomicAdd(&orow[j * 16], acc[i][j][r] * w);
      }
    }
  }
}

// ---------------- finalize: fp32 accum -> out (dual dtype), lb scalar ------
__global__ __launch_bounds__(256) void finalize_k(
    const float* __restrict__ accb, const float* __restrict__ usage,
    void* __restrict__ out, const int* __restrict__ flag) {
  int f = *flag;
  size_t idx = (size_t)blockIdx.x * 256 + threadIdx.x;
  float4 v = ((const float4*)accb)[idx];
  float lb = 0.0f;
  if (idx == 0) {
    for (int e = 0; e < 8; e++) {
      float d = usage[e] * (1.0f / 8192.0f) - 0.125f;
      lb += d * d;
    }
    lb *= 0.01f * 0.125f;
  }
  if (f) {
    u16* o = (u16*)out;
    ushort4 ov;
    ov.x = f2bf(v.x); ov.y = f2bf(v.y); ov.z = f2bf(v.z); ov.w = f2bf(v.w);
    ((ushort4*)o)[idx] = ov;
    if (idx == 0) o[(size_t)T_TOK * DM] = f2bf(lb);
  } else {
    float* o = (float*)out;
    ((float4*)o)[idx] = v;
    if (idx == 0) o[(size_t)T_TOK * DM] = lb;
  }
}

extern "C" void kernel_launch(void* const* d_in, const int* in_sizes, int n_in,
                              void* d_out, int out_size, void* d_ws, size_t ws_size,
                              hipStream_t stream) {
  const void* x  = d_in[0];
  const void* Wr = d_in[1];
  const void* Wg = d_in[2];
  const void* Wu = d_in[3];
  const void* Wx = d_in[4];
  const void* Wd = d_in[5];
  const void* al = d_in[6];
  char* ws = (char*)d_ws;

  int*   counts  = (int*)(ws + 0);           // 32
  float* usage   = (float*)(ws + 32);        // 32
  int*   flag    = (int*)(ws + 64);          // pad to 128
  float* accb    = (float*)(ws + 128);       // 33,554,432
  int*   offs    = (int*)(ws + 33554560);    // 64
  int*   tok_ids = (int*)(ws + 33554624);    // 262,144
  float* tok_w   = (float*)(ws + 33816768);  // 262,144
  u16*   alphab  = (u16*)(ws + 34078912);    // 64
  u16*   xb      = (u16*)(ws + 34078976);    // 16,777,216
  u16*   comb    = (u16*)(ws + 50856192);    // 46,137,344
  u16*   WgT     = (u16*)(ws + 96993536);    // 23,068,672
  u16*   WuT     = (u16*)(ws + 120062208);   // 23,068,672
  u16*   WdT     = (u16*)(ws + 143130880);   // 23,068,672
  float* probs   = (float*)(ws + 166199552); // 262,144
  u16*   WxT     = (u16*)(ws + 166461696);   // 23,068,672 (touched only if alpha!=1)

  hipMemsetAsync(ws, 0, 33554560, stream);  // counts+usage+flag+accb

  dim3 b256(256, 1, 1);
  detect_k<<<dim3(1), dim3(64), 0, stream>>>((const u16*)x, flag);
  conv_alpha_k<<<dim3(1), dim3(64), 0, stream>>>(al, alphab, flag);
  conv_x_k<<<dim3(4096), b256, 0, stream>>>(x, xb, flag);
  transpose_k<<<dim3(HD / 64, DM / 64, NE), b256, 0, stream>>>(Wg, WgT, DM, HD, alphab, 2, flag);
  transpose_k<<<dim3(HD / 64, DM / 64, NE), b256, 0, stream>>>(Wu, WuT, DM, HD, alphab, 0, flag);
  transpose_k<<<dim3(HD / 64, DM / 64, NE), b256, 0, stream>>>(Wx, WxT, DM, HD, alphab, 1, flag);
  transpose_k<<<dim3(DM / 64, HD / 64, NE), b256, 0, stream>>>(Wd, WdT, HD, DM, alphab, 0, flag);
  rdot_k<<<dim3(T_TOK / 4), b256, 0, stream>>>(x, Wr, probs, flag);
  build_k<<<dim3(T_TOK / 256), b256, 0, stream>>>(probs, counts, usage, tok_ids, tok_w);
  scan_k<<<dim3(1), dim3(64), 0, stream>>>(counts, offs);
  stageA2_k<<<dim3(HD / 128, T_TOK / 128, NE), b256, 0, stream>>>(
      x, xb, WgT, WuT, alphab, counts, offs, tok_ids, comb, flag);
  stageA_k<<<dim3(HD / 64, T_TOK / 128, NE), b256, 0, stream>>>(
      x, xb, WgT, WuT, WxT, alphab, counts, offs, tok_ids, comb, flag);
  stageB_k<<<dim3(DM / 128, T_TOK / 128, NE), b256, 0, stream>>>(
      comb, WdT, counts, offs, tok_ids, tok_w, accb);
  finalize_k<<<dim3((T_TOK * DM / 4) / 256), b256, 0, stream>>>(accb, usage, d_out, flag);
}

// Round 7
// 469.436 us; speedup vs baseline: 1.6089x; 1.0833x over previous
//
#include <hip/hip_runtime.h>
#include <stdint.h>

typedef unsigned short u16;
typedef __attribute__((ext_vector_type(8))) short short8;
typedef __attribute__((ext_vector_type(4))) float floatx4;

#define T_TOK 8192
#define DM 1024
#define NE 8
#define HD 1408
#define LDA 72  // padded stride for the fallback (register-staged) kernel only

__device__ __forceinline__ float bf2f(u16 u) {
  union { float f; uint32_t i; } v; v.i = ((uint32_t)u) << 16; return v.f;
}
__device__ __forceinline__ u16 f2bf(float f) {
  union { float f; uint32_t i; } v; v.f = f;
  uint32_t r = v.i + 0x7fffu + ((v.i >> 16) & 1u);
  return (u16)(r >> 16);
}
__device__ __forceinline__ void llds16(const void* g, void* l) {
  __builtin_amdgcn_global_load_lds((const __attribute__((address_space(1))) void*)g,
                                   (__attribute__((address_space(3))) void*)l, 16, 0, 0);
}
__device__ __forceinline__ floatx4 mfma16(short8 a, short8 b, floatx4 c) {
  return __builtin_amdgcn_mfma_f32_16x16x32_bf16(a, b, c, 0, 0, 0);
}

// ---------------- dtype detect: bf16 vs fp32 input arrays ------------------
__global__ void detect_k(const u16* __restrict__ xraw, int* __restrict__ flag) {
  int lane = threadIdx.x & 63;
  u16 w = xraw[lane * 2];
  int ex = (w >> 7) & 0xFF;
  bool hit = (ex >= 100 && ex <= 135);
  unsigned long long m = __ballot(hit);
  if (lane == 0) *flag = (__popcll(m) >= 40) ? 1 : 0;
}

// ---------------- alpha convert -> canonical bf16 --------------------------
__global__ void conv_alpha_k(const void* __restrict__ araw, u16* __restrict__ ab,
                             const int* __restrict__ flag) {
  int f = *flag;
  if (threadIdx.x < NE) {
    ab[threadIdx.x] = f ? ((const u16*)araw)[threadIdx.x]
                        : f2bf(((const float*)araw)[threadIdx.x]);
  }
}

// ---------------- x convert -> canonical bf16 (fp32 case only) -------------
__global__ __launch_bounds__(256) void conv_x_k(const void* __restrict__ xraw,
                                                u16* __restrict__ xb,
                                                const int* __restrict__ flag) {
  if (*flag) return;
  size_t base = ((size_t)blockIdx.x * 256 + threadIdx.x) * 8;
  const float* s = (const float*)xraw + base;
  float4 v0 = *(const float4*)s;
  float4 v1 = *(const float4*)(s + 4);
  ushort4 o0, o1;
  o0.x = f2bf(v0.x); o0.y = f2bf(v0.y); o0.z = f2bf(v0.z); o0.w = f2bf(v0.w);
  o1.x = f2bf(v1.x); o1.y = f2bf(v1.y); o1.z = f2bf(v1.z); o1.w = f2bf(v1.w);
  *(ushort4*)(xb + base) = o0;
  *(ushort4*)(xb + base + 4) = o1;
}

// ---------------- transpose+convert: src [E][R][C] -> dst bf16 [E][C][R] ---
// v2: vectorized reads (ushort4/float4) + 16B short8 stores.
__global__ __launch_bounds__(256) void transpose_k(
    const void* __restrict__ src, u16* __restrict__ dst, int R, int C,
    const u16* __restrict__ alphab, int mode, const int* __restrict__ flag) {
  int e = blockIdx.z;
  if (mode) {
    float a = bf2f(alphab[e]);
    if (mode == 1 && a == 1.0f) return;  // Wx unused when alpha==1
    if (mode == 2 && a == 0.0f) return;  // Wg unused when alpha==0
  }
  int f = *flag;
  __shared__ u16 tile[64][68];  // stride 68: 8B-aligned rows, bank stride 2
  u16* d = dst + (size_t)e * R * C;
  int c0 = blockIdx.x * 64, r0 = blockIdx.y * 64;
  int tid = threadIdx.x;
  int r = tid >> 4, c4 = (tid & 15) * 4;
  if (f) {
    const u16* s = (const u16*)src + (size_t)e * R * C;
    for (int rr = r; rr < 64; rr += 16) {
      ushort4 v = *(const ushort4*)&s[(size_t)(r0 + rr) * C + c0 + c4];
      *(ushort4*)&tile[rr][c4] = v;
    }
  } else {
    const float* s = (const float*)src + (size_t)e * R * C;
    for (int rr = r; rr < 64; rr += 16) {
      float4 v = *(const float4*)&s[(size_t)(r0 + rr) * C + c0 + c4];
      ushort4 o; o.x = f2bf(v.x); o.y = f2bf(v.y); o.z = f2bf(v.z); o.w = f2bf(v.w);
      *(ushort4*)&tile[rr][c4] = o;
    }
  }
  __syncthreads();
  int rg = (tid & 7) * 8, ii = tid >> 3;
  for (int i2 = ii; i2 < 64; i2 += 32) {
    short8 v;
    #pragma unroll
    for (int t = 0; t < 8; t++) ((u16*)&v)[t] = tile[rg + t][i2];
    *(short8*)&d[(size_t)(c0 + i2) * R + r0 + rg] = v;
  }
}

// ---------------- router phase 1: logits+softmax, NO atomics ---------------
__global__ __launch_bounds__(256) void rdot_k(
    const void* __restrict__ x, const void* __restrict__ Wr,
    float* __restrict__ probs, const int* __restrict__ flag) {
  int wave = threadIdx.x >> 6, lane = threadIdx.x & 63;
  int t = blockIdx.x * 4 + wave;
  int f = *flag;
  float acc[8];
  #pragma unroll
  for (int e = 0; e < 8; e++) acc[e] = 0.0f;
  if (f) {
    const u16* xr = (const u16*)x + (size_t)t * DM;
    const u16* wr = (const u16*)Wr;
    #pragma unroll
    for (int i = 0; i < 16; i++) {
      int d = i * 64 + lane;
      float xv = bf2f(xr[d]);
      uint4 wv = *(const uint4*)(wr + (size_t)d * 8);
      acc[0] += xv * bf2f((u16)(wv.x & 0xffff));
      acc[1] += xv * bf2f((u16)(wv.x >> 16));
      acc[2] += xv * bf2f((u16)(wv.y & 0xffff));
      acc[3] += xv * bf2f((u16)(wv.y >> 16));
      acc[4] += xv * bf2f((u16)(wv.z & 0xffff));
      acc[5] += xv * bf2f((u16)(wv.z >> 16));
      acc[6] += xv * bf2f((u16)(wv.w & 0xffff));
      acc[7] += xv * bf2f((u16)(wv.w >> 16));
    }
  } else {
    const float* xr = (const float*)x + (size_t)t * DM;
    const float* wr = (const float*)Wr;
    #pragma unroll
    for (int i = 0; i < 16; i++) {
      int d = i * 64 + lane;
      float xv = xr[d];
      float4 w0 = *(const float4*)(wr + (size_t)d * 8);
      float4 w1 = *(const float4*)(wr + (size_t)d * 8 + 4);
      acc[0] += xv * w0.x; acc[1] += xv * w0.y;
      acc[2] += xv * w0.z; acc[3] += xv * w0.w;
      acc[4] += xv * w1.x; acc[5] += xv * w1.y;
      acc[6] += xv * w1.z; acc[7] += xv * w1.w;
    }
  }
  #pragma unroll
  for (int e = 0; e < 8; e++) {
    #pragma unroll
    for (int s = 32; s; s >>= 1) acc[e] += __shfl_xor(acc[e], s, 64);
  }
  float mx = acc[0];
  #pragma unroll
  for (int e = 1; e < 8; e++) mx = fmaxf(mx, acc[e]);
  float p[8], sum = 0.0f;
  #pragma unroll
  for (int e = 0; e < 8; e++) { p[e] = __expf(acc[e] - mx); sum += p[e]; }
  float inv = 1.0f / sum;
  if (lane < 8) probs[(size_t)t * 8 + lane] = p[lane] * inv;
}

// ---------------- router phase 2: build expert lists (few atomics) ---------
__global__ __launch_bounds__(256) void build_k(
    const float* __restrict__ probs, int* __restrict__ counts,
    float* __restrict__ usage, int* __restrict__ tok_ids,
    float* __restrict__ tok_w) {
  __shared__ int sCnt[8];
  __shared__ int sBase[8];
  __shared__ float sUse[8];
  int tid = threadIdx.x;
  if (tid < 8) { sCnt[tid] = 0; sUse[tid] = 0.0f; }
  __syncthreads();

  int t = blockIdx.x * 256 + tid;
  float4 p0 = *(const float4*)(probs + (size_t)t * 8);
  float4 p1 = *(const float4*)(probs + (size_t)t * 8 + 4);
  float p[8] = {p0.x, p0.y, p0.z, p0.w, p1.x, p1.y, p1.z, p1.w};

  #pragma unroll
  for (int e = 0; e < 8; e++) {
    float v = p[e];
    #pragma unroll
    for (int s = 32; s; s >>= 1) v += __shfl_xor(v, s, 64);
    if ((tid & 63) == 0) atomicAdd(&sUse[e], v);
  }

  int e0 = 0;
  #pragma unroll
  for (int e = 1; e < 8; e++) if (p[e] > p[e0]) e0 = e;
  int e1 = (e0 == 0) ? 1 : 0;
  #pragma unroll
  for (int e = 0; e < 8; e++) if (e != e0 && p[e] > p[e1]) e1 = e;
  float s2 = 1.0f / (p[e0] + p[e1]);

  int s0 = atomicAdd(&sCnt[e0], 1);
  int s1 = atomicAdd(&sCnt[e1], 1);
  __syncthreads();
  if (tid < 8) {
    sBase[tid] = atomicAdd(&counts[tid], sCnt[tid]);
    atomicAdd(&usage[tid], sUse[tid]);
  }
  __syncthreads();
  int i0 = sBase[e0] + s0;
  tok_ids[e0 * T_TOK + i0] = t; tok_w[e0 * T_TOK + i0] = p[e0] * s2;
  int i1 = sBase[e1] + s1;
  tok_ids[e1 * T_TOK + i1] = t; tok_w[e1 * T_TOK + i1] = p[e1] * s2;
}

__global__ void scan_k(const int* __restrict__ counts, int* __restrict__ offs) {
  if (threadIdx.x == 0) {
    int s = 0;
    for (int e = 0; e < 8; e++) { offs[e] = s; s += counts[e]; }
    offs[8] = s;
  }
}

// ---------------- stage A lean (alpha==1): async + XOR-swizzled LDS --------
// 1D grid, e = bid&7 (XCD affinity). Swizzle: thread f stages global k-seg
// ((f&7)^((f>>3)&7)) into LDS slot (f&7); reader fetches slot kseg^(row&7).
__global__ __launch_bounds__(256, 2) void stageA2_k(
    const void* __restrict__ xraw, const u16* __restrict__ xb,
    const u16* __restrict__ WgT, const u16* __restrict__ WuT,
    const u16* __restrict__ alphab, const int* __restrict__ counts,
    const int* __restrict__ offs, const int* __restrict__ tok_ids,
    u16* __restrict__ comb, const int* __restrict__ flag) {
  int bid = blockIdx.x;
  int e = bid & 7;
  float aE = bf2f(alphab[e]);
  if (aE != 1.0f) return;  // fallback kernel handles alpha != 1
  int t2 = bid >> 3;
  int h0 = (t2 % (HD / 128)) * 128;
  int m0 = (t2 / (HD / 128)) * 128;
  int cnt = counts[e];
  if (m0 >= cnt) return;
  int rem = cnt - m0;
  const u16* x = (*flag) ? (const u16*)xraw : xb;

  alignas(16) __shared__ u16 sA[128 * 64];
  alignas(16) __shared__ u16 sG[128 * 64];
  alignas(16) __shared__ u16 sU[128 * 64];
  __shared__ int sTok[128];

  int tid = threadIdx.x;
  if (tid < 128)
    sTok[tid] = tok_ids[e * T_TOK + ((tid < rem) ? (m0 + tid) : m0)];
  __syncthreads();

  const u16* wg = WgT + (size_t)e * HD * DM;
  const u16* wu = WuT + (size_t)e * HD * DM;

  int lane = tid & 63, wave = tid >> 6;
  int wm = wave & 1, wn = wave >> 1;
  int lr = lane & 15, quad = lane >> 4;

  // staging: XOR-swizzled global source, lane-linear LDS dest
  const u16* aptr[4]; const u16* gptr[4]; const u16* uptr[4];
  u16 *dA[4], *dG[4], *dU[4];
  #pragma unroll
  for (int i = 0; i < 4; i++) {
    int f = tid + 256 * i;
    int row = f >> 3;
    int seg = (f & 7) ^ (row & 7);
    aptr[i] = x + (size_t)sTok[row] * DM + seg * 8;
    gptr[i] = wg + (size_t)(h0 + row) * DM + seg * 8;
    uptr[i] = wu + (size_t)(h0 + row) * DM + seg * 8;
    dA[i] = &sA[f * 8]; dG[i] = &sG[f * 8]; dU[i] = &sU[f * 8];
  }

  floatx4 accG[4][4], accU[4][4];
  #pragma unroll
  for (int i = 0; i < 4; i++)
    #pragma unroll
    for (int j = 0; j < 4; j++) { accG[i][j] = (floatx4)0.0f; accU[i][j] = (floatx4)0.0f; }

  for (int kt = 0; kt < DM / 64; kt++) {
    int k0 = kt * 64;
    __syncthreads();
    #pragma unroll
    for (int i = 0; i < 4; i++) llds16(aptr[i] + k0, dA[i]);
    #pragma unroll
    for (int i = 0; i < 4; i++) llds16(uptr[i] + k0, dU[i]);
    #pragma unroll
    for (int i = 0; i < 4; i++) llds16(gptr[i] + k0, dG[i]);
    __syncthreads();
    #pragma unroll
    for (int kk = 0; kk < 2; kk++) {
      int slot = ((kk * 4 + quad) ^ (lr & 7)) * 8;
      short8 a[4];
      #pragma unroll
      for (int i = 0; i < 4; i++)
        a[i] = *(const short8*)&sA[(wm * 64 + i * 16 + lr) * 64 + slot];
      #pragma unroll
      for (int j = 0; j < 4; j++) {
        int nb = (wn * 64 + j * 16 + lr) * 64 + slot;
        short8 bu = *(const short8*)&sU[nb];
        #pragma unroll
        for (int i = 0; i < 4; i++) accU[i][j] = mfma16(a[i], bu, accU[i][j]);
        short8 bg = *(const short8*)&sG[nb];
        #pragma unroll
        for (int i = 0; i < 4; i++) accG[i][j] = mfma16(a[i], bg, accG[i][j]);
      }
    }
  }

  size_t rbase = (size_t)(offs[e] + m0);
  #pragma unroll
  for (int i = 0; i < 4; i++) {
    #pragma unroll
    for (int r = 0; r < 4; r++) {
      int row = wm * 64 + i * 16 + quad * 4 + r;
      if (row < rem) {
        u16* cp = comb + (rbase + row) * HD + h0 + wn * 64 + lr;
        #pragma unroll
        for (int j = 0; j < 4; j++) {
          float g = accG[i][j][r], u = accU[i][j][r];
          float sg = g / (1.0f + __expf(-g));
          cp[j * 16] = f2bf(u * sg);
        }
      }
    }
  }
}

// ---------------- stage A fallback (alpha != 1): register-staged, BN=64 ----
__global__ __launch_bounds__(256, 2) void stageA_k(
    const void* __restrict__ xraw, const u16* __restrict__ xb,
    const u16* __restrict__ WgT, const u16* __restrict__ WuT,
    const u16* __restrict__ WxT, const u16* __restrict__ alphab,
    const int* __restrict__ counts, const int* __restrict__ offs,
    const int* __restrict__ tok_ids, u16* __restrict__ comb,
    const int* __restrict__ flag) {
  int e = blockIdx.z;
  float aE = bf2f(alphab[e]);
  if (aE == 1.0f) return;  // lean kernel handles alpha == 1
  int cnt = counts[e];
  int m0 = blockIdx.y * 128;
  if (m0 >= cnt) return;
  int h0 = blockIdx.x * 64;
  int rem = cnt - m0;
  const u16* x = (*flag) ? (const u16*)xraw : xb;

  alignas(16) __shared__ u16 sA[128 * LDA];
  alignas(16) __shared__ u16 sG[64 * LDA];
  alignas(16) __shared__ u16 sU[64 * LDA];
  alignas(16) __shared__ u16 sX[64 * LDA];
  __shared__ int sTok[128];

  int tid = threadIdx.x;
  if (tid < 128)
    sTok[tid] = tok_ids[e * T_TOK + ((tid < rem) ? (m0 + tid) : m0)];
  __syncthreads();

  bool needG = (aE != 0.0f);

  const u16* wg = WgT + (size_t)e * HD * DM;
  const u16* wu = WuT + (size_t)e * HD * DM;
  const u16* wx = WxT + (size_t)e * HD * DM;

  int lane = tid & 63, wave = tid >> 6;
  int wm = wave & 1, wn = wave >> 1;
  int lr = lane & 15, quad = lane >> 4;

  int rowA[4], segA[4], rowW[2], segW[2];
  #pragma unroll
  for (int i = 0; i < 4; i++) { int f = tid + 256 * i; rowA[i] = f >> 3; segA[i] = f & 7; }
  #pragma unroll
  for (int i = 0; i < 2; i++) { int f = tid + 256 * i; rowW[i] = f >> 3; segW[i] = f & 7; }

  floatx4 accG[4][2], accU[4][2], accX[4][2];
  #pragma unroll
  for (int i = 0; i < 4; i++)
    #pragma unroll
    for (int j = 0; j < 2; j++) {
      accG[i][j] = (floatx4)0.0f; accU[i][j] = (floatx4)0.0f; accX[i][j] = (floatx4)0.0f;
    }

  short8 rA[4], rU[2], rG[2], rX[2];
  #pragma unroll
  for (int i = 0; i < 4; i++)
    rA[i] = *(const short8*)(x + (size_t)sTok[rowA[i]] * DM + segA[i] * 8);
  #pragma unroll
  for (int i = 0; i < 2; i++) {
    size_t go = (size_t)(h0 + rowW[i]) * DM + segW[i] * 8;
    rU[i] = *(const short8*)(wu + go);
    if (needG) rG[i] = *(const short8*)(wg + go);
    rX[i] = *(const short8*)(wx + go);
  }

  const int NK = DM / 64;
  for (int kt = 0; kt < NK; kt++) {
    __syncthreads();
    #pragma unroll
    for (int i = 0; i < 4; i++)
      *(short8*)&sA[rowA[i] * LDA + segA[i] * 8] = rA[i];
    #pragma unroll
    for (int i = 0; i < 2; i++) {
      *(short8*)&sU[rowW[i] * LDA + segW[i] * 8] = rU[i];
      if (needG) *(short8*)&sG[rowW[i] * LDA + segW[i] * 8] = rG[i];
      *(short8*)&sX[rowW[i] * LDA + segW[i] * 8] = rX[i];
    }
    __syncthreads();
    if (kt + 1 < NK) {
      int k0 = (kt + 1) * 64;
      #pragma unroll
      for (int i = 0; i < 4; i++)
        rA[i] = *(const short8*)(x + (size_t)sTok[rowA[i]] * DM + k0 + segA[i] * 8);
      #pragma unroll
      for (int i = 0; i < 2; i++) {
        size_t go = (size_t)(h0 + rowW[i]) * DM + k0 + segW[i] * 8;
        rU[i] = *(const short8*)(wu + go);
        if (needG) rG[i] = *(const short8*)(wg + go);
        rX[i] = *(const short8*)(wx + go);
      }
    }
    #pragma unroll
    for (int kk = 0; kk < 2; kk++) {
      int kb = kk * 32 + quad * 8;
      short8 a[4];
      #pragma unroll
      for (int i = 0; i < 4; i++)
        a[i] = *(const short8*)&sA[(wm * 64 + i * 16 + lr) * LDA + kb];
      #pragma unroll
      for (int j = 0; j < 2; j++) {
        int nb = (wn * 32 + j * 16 + lr) * LDA + kb;
        short8 bu = *(const short8*)&sU[nb];
        #pragma unroll
        for (int i = 0; i < 4; i++) accU[i][j] = mfma16(a[i], bu, accU[i][j]);
        if (needG) {
          short8 bg = *(const short8*)&sG[nb];
          #pragma unroll
          for (int i = 0; i < 4; i++) accG[i][j] = mfma16(a[i], bg, accG[i][j]);
        }
        short8 bx = *(const short8*)&sX[nb];
        #pragma unroll
        for (int i = 0; i < 4; i++) accX[i][j] = mfma16(a[i], bx, accX[i][j]);
      }
    }
  }

  float a1 = aE, a2 = 1.0f - aE;
  size_t rbase = (size_t)(offs[e] + m0);
  #pragma unroll
  for (int i = 0; i < 4; i++) {
    #pragma unroll
    for (int r = 0; r < 4; r++) {
      int row = wm * 64 + i * 16 + quad * 4 + r;
      if (row < rem) {
        u16* cp = comb + (rbase + row) * HD + h0 + wn * 32 + lr;
        #pragma unroll
        for (int j = 0; j < 2; j++) {
          float g = accG[i][j][r], u = accU[i][j][r], xx = accX[i][j][r];
          float sg = g / (1.0f + __expf(-g));
          float sx = xx / (1.0f + __expf(-xx));
          cp[j * 16] = f2bf(u * (a1 * sg + a2 * sx));
        }
      }
    }
  }
}

// ---------------- stage B: combined @ WdT, async + XOR-swizzled LDS --------
__global__ __launch_bounds__(256, 2) void stageB_k(
    const u16* __restrict__ comb, const u16* __restrict__ WdT,
    const int* __restrict__ counts, const int* __restrict__ offs,
    const int* __restrict__ tok_ids, const float* __restrict__ tok_w,
    float* __restrict__ accb) {
  int bid = blockIdx.x;
  int e = bid & 7;
  int t2 = bid >> 3;
  int d0 = (t2 % (DM / 128)) * 128;
  int m0 = (t2 / (DM / 128)) * 128;
  int cnt = counts[e];
  if (m0 >= cnt) return;
  int rem = cnt - m0;

  alignas(16) __shared__ u16 sA[128 * 64];
  alignas(16) __shared__ u16 sB[128 * 64];
  __shared__ int sTok[128];
  __shared__ float sW[128];

  int tid = threadIdx.x;
  if (tid < 128) {
    bool v = tid < rem;
    sTok[tid] = v ? tok_ids[e * T_TOK + m0 + tid] : 0;
    sW[tid] = v ? tok_w[e * T_TOK + m0 + tid] : 0.0f;
  }
  __syncthreads();

  const u16* ca = comb + (size_t)(offs[e] + m0) * HD;
  const u16* wd = WdT + (size_t)e * DM * HD;

  int lane = tid & 63, wave = tid >> 6;
  int wm = wave & 1, wn = wave >> 1;
  int lr = lane & 15, quad = lane >> 4;

  const u16* aptr[4]; const u16* bptr[4];
  u16 *dA[4], *dB[4];
  #pragma unroll
  for (int i = 0; i < 4; i++) {
    int f = tid + 256 * i;
    int row = f >> 3;
    int seg = (f & 7) ^ (row & 7);
    int rc = (row < rem) ? row : 0;
    aptr[i] = ca + (size_t)rc * HD + seg * 8;
    bptr[i] = wd + (size_t)(d0 + row) * HD + seg * 8;
    dA[i] = &sA[f * 8]; dB[i] = &sB[f * 8];
  }

  floatx4 acc[4][4];
  #pragma unroll
  for (int i = 0; i < 4; i++)
    #pragma unroll
    for (int j = 0; j < 4; j++) acc[i][j] = (floatx4)0.0f;

  for (int kt = 0; kt < HD / 64; kt++) {
    int k0 = kt * 64;
    __syncthreads();
    #pragma unroll
    for (int i = 0; i < 4; i++) llds16(aptr[i] + k0, dA[i]);
    #pragma unroll
    for (int i = 0; i < 4; i++) llds16(bptr[i] + k0, dB[i]);
    __syncthreads();
    #pragma unroll
    for (int kk = 0; kk < 2; kk++) {
      int slot = ((kk * 4 + quad) ^ (lr & 7)) * 8;
      short8 a[4];
      #pragma unroll
      for (int i = 0; i < 4; i++)
        a[i] = *(const short8*)&sA[(wm * 64 + i * 16 + lr) * 64 + slot];
      #pragma unroll
      for (int j = 0; j < 4; j++) {
        short8 b = *(const short8*)&sB[(wn * 64 + j * 16 + lr) * 64 + slot];
        #pragma unroll
        for (int i = 0; i < 4; i++) acc[i][j] = mfma16(a[i], b, acc[i][j]);
      }
    }
  }

  #pragma unroll
  for (int i = 0; i < 4; i++) {
    #pragma unroll
    for (int r = 0; r < 4; r++) {
      int row = wm * 64 + i * 16 + quad * 4 + r;
      if (row < rem) {
        int t = sTok[row];
        float w = sW[row];
        float* orow = accb + (size_t)t * DM + d0 + wn * 64 + lr;
        #pragma unroll
        for (int j = 0; j < 4; j++)
          atomicAdd(&orow[j * 16], acc[i][j][r] * w);
      }
    }
  }
}

// ---------------- finalize: fp32 accum -> out (dual dtype), lb scalar ------
__global__ __launch_bounds__(256) void finalize_k(
    const float* __restrict__ accb, const float* __restrict__ usage,
    void* __restrict__ out, const int* __restrict__ flag) {
  int f = *flag;
  size_t idx = (size_t)blockIdx.x * 256 + threadIdx.x;
  float4 v = ((const float4*)accb)[idx];
  float lb = 0.0f;
  if (idx == 0) {
    for (int e = 0; e < 8; e++) {
      float d = usage[e] * (1.0f / 8192.0f) - 0.125f;
      lb += d * d;
    }
    lb *= 0.01f * 0.125f;
  }
  if (f) {
    u16* o = (u16*)out;
    ushort4 ov;
    ov.x = f2bf(v.x); ov.y = f2bf(v.y); ov.z = f2bf(v.z); ov.w = f2bf(v.w);
    ((ushort4*)o)[idx] = ov;
    if (idx == 0) o[(size_t)T_TOK * DM] = f2bf(lb);
  } else {
    float* o = (float*)out;
    ((float4*)o)[idx] = v;
    if (idx == 0) o[(size_t)T_TOK * DM] = lb;
  }
}

extern "C" void kernel_launch(void* const* d_in, const int* in_sizes, int n_in,
                              void* d_out, int out_size, void* d_ws, size_t ws_size,
                              hipStream_t stream) {
  const void* x  = d_in[0];
  const void* Wr = d_in[1];
  const void* Wg = d_in[2];
  const void* Wu = d_in[3];
  const void* Wx = d_in[4];
  const void* Wd = d_in[5];
  const void* al = d_in[6];
  char* ws = (char*)d_ws;

  int*   counts  = (int*)(ws + 0);           // 32
  float* usage   = (float*)(ws + 32);        // 32
  int*   flag    = (int*)(ws + 64);          // pad to 128
  float* accb    = (float*)(ws + 128);       // 33,554,432
  int*   offs    = (int*)(ws + 33554560);    // 64
  int*   tok_ids = (int*)(ws + 33554624);    // 262,144
  float* tok_w   = (float*)(ws + 33816768);  // 262,144
  u16*   alphab  = (u16*)(ws + 34078912);    // 64
  u16*   xb      = (u16*)(ws + 34078976);    // 16,777,216
  u16*   comb    = (u16*)(ws + 50856192);    // 46,137,344
  u16*   WgT     = (u16*)(ws + 96993536);    // 23,068,672
  u16*   WuT     = (u16*)(ws + 120062208);   // 23,068,672
  u16*   WdT     = (u16*)(ws + 143130880);   // 23,068,672
  float* probs   = (float*)(ws + 166199552); // 262,144
  u16*   WxT     = (u16*)(ws + 166461696);   // 23,068,672 (touched only if alpha!=1)

  hipMemsetAsync(ws, 0, 33554560, stream);  // counts+usage+flag+accb

  dim3 b256(256, 1, 1);
  detect_k<<<dim3(1), dim3(64), 0, stream>>>((const u16*)x, flag);
  conv_alpha_k<<<dim3(1), dim3(64), 0, stream>>>(al, alphab, flag);
  conv_x_k<<<dim3(4096), b256, 0, stream>>>(x, xb, flag);
  transpose_k<<<dim3(HD / 64, DM / 64, NE), b256, 0, stream>>>(Wg, WgT, DM, HD, alphab, 2, flag);
  transpose_k<<<dim3(HD / 64, DM / 64, NE), b256, 0, stream>>>(Wu, WuT, DM, HD, alphab, 0, flag);
  transpose_k<<<dim3(HD / 64, DM / 64, NE), b256, 0, stream>>>(Wx, WxT, DM, HD, alphab, 1, flag);
  transpose_k<<<dim3(DM / 64, HD / 64, NE), b256, 0, stream>>>(Wd, WdT, HD, DM, alphab, 0, flag);
  rdot_k<<<dim3(T_TOK / 4), b256, 0, stream>>>(x, Wr, probs, flag);
  build_k<<<dim3(T_TOK / 256), b256, 0, stream>>>(probs, counts, usage, tok_ids, tok_w);
  scan_k<<<dim3(1), dim3(64), 0, stream>>>(counts, offs);
  stageA2_k<<<dim3(NE * (HD / 128) * (T_TOK / 128)), b256, 0, stream>>>(
      x, xb, WgT, WuT, alphab, counts, offs, tok_ids, comb, flag);
  stageA_k<<<dim3(HD / 64, T_TOK / 128, NE), b256, 0, stream>>>(
      x, xb, WgT, WuT, WxT, alphab, counts, offs, tok_ids, comb, flag);
  stageB_k<<<dim3(NE * (DM / 128) * (T_TOK / 128)), b256, 0, stream>>>(
      comb, WdT, counts, offs, tok_ids, tok_w, accb);
  finalize_k<<<dim3((T_TOK * DM / 4) / 256), b256, 0, stream>>>(accb, usage, d_out, flag);
}